// Round 1
// baseline (381.095 us; speedup 1.0000x reference)
//
#include <hip/hip_runtime.h>
#include <cmath>

#define BB 16
#define PP 4096
#define QQ 1024
#define DD 256

typedef __attribute__((ext_vector_type(8))) short short8;
typedef __attribute__((ext_vector_type(4))) float floatx4;
typedef __attribute__((ext_vector_type(4))) _Float16 half4;
typedef __attribute__((ext_vector_type(4))) unsigned short ushort4v;

static __device__ inline ushort bf16_rne(float x) {
  unsigned u = __float_as_uint(x);
  unsigned r = (u + 0x7fffu + ((u >> 16) & 1u)) >> 16;
  return (ushort)r;
}
static __device__ inline float bf16f(ushort h) { return __uint_as_float(((unsigned)h) << 16); }

static __device__ inline float ftanh(float x) {
  float e = __expf(2.0f * x);
  return 1.0f - 2.0f * __builtin_amdgcn_rcpf(e + 1.0f);
}

static __device__ inline void gl16(const void* g, void* l) {
  __builtin_amdgcn_global_load_lds(
      (const __attribute__((address_space(1))) unsigned int*)g,
      (__attribute__((address_space(3))) unsigned int*)l, 16, 0, 0);
}

// ---------------------------------------------------------------------------
// kQprep: Q -> per-(b,32q-tile) 48KB blobs: [SQhi 16K | SQlo 16K | TQhi 16K].
//  SQ: row-major hi/lo, granule j of row r at slot j^(r&7).
//  TQ: transposed [d][32q] bf16-hi only, granule k at slot k^((d>>1)&3).
// ---------------------------------------------------------------------------
__global__ __launch_bounds__(256) void kQprep(
    const float* __restrict__ ques, ushort* __restrict__ qb)
{
  const int b = blockIdx.y, qt = blockIdx.x;
  __shared__ float tile[32][260];
  const int tid = threadIdx.x;
  const float* src = ques + ((size_t)b * QQ + qt * 32) * DD;
  for (int i = tid; i < 32 * 64; i += 256) {
    int r = i >> 6, c = (i & 63) << 2;
    *(float4*)&tile[r][c] = *(const float4*)(src + r * DD + c);
  }
  __syncthreads();
  ushort* blob = qb + (size_t)(b * 32 + qt) * 24576;
  {
    int r = tid >> 3;
    int j0 = (tid & 7) * 4;
#pragma unroll
    for (int jj = 0; jj < 4; ++jj) {
      int j = j0 + jj;
      ushort h8[8], l8[8];
#pragma unroll
      for (int e = 0; e < 8; ++e) {
        float x = tile[r][j * 8 + e];
        ushort h = bf16_rne(x);
        h8[e] = h; l8[e] = bf16_rne(x - bf16f(h));
      }
      int g = r * 32 + (j ^ (r & 7));
      *(uint4*)&blob[(size_t)g * 8] = *(uint4*)h8;
      *(uint4*)&blob[8192 + (size_t)g * 8] = *(uint4*)l8;
    }
  }
  {
    int d = tid;
    int s = (d >> 1) & 3;
    ushort h32[32];
#pragma unroll
    for (int r = 0; r < 32; ++r) h32[r] = bf16_rne(tile[r][d]);
#pragma unroll
    for (int k = 0; k < 4; ++k)
      *(uint4*)&blob[16384 + (size_t)d * 32 + (k ^ s) * 8] = *(uint4*)&h32[k * 8];
  }
}

// ---------------------------------------------------------------------------
// kA: flash attention, LDS-traffic-minimized wave decomposition.
// 512 thr = 8 waves. Double-buffered 48KB Q tiles + 16KB split-hi/lo P buffer.
// GEMM1: wave = 1 q-tile x 2 p-tiles (A-frags read once, used for 2 B-tiles).
// GEMM2: wave = 4 p-tiles x 4 d-tiles (64p x 64d); P transits LDS (hi/lo split
//        so reads are direct short8 A-frags, no unpack).
// Per iter: DMA(t+1) | GEMM1(t) | softmax(t) | P-write | lgkm-barrier |
//           GEMM2(t) | syncthreads.  vmcnt NOT drained at mid-barrier.
// ---------------------------------------------------------------------------
__global__ __launch_bounds__(512, 2) void kA(
    const float* __restrict__ pass, const ushort* __restrict__ qb,
    const float* __restrict__ w_attn,
    _Float16* __restrict__ first_h, _Float16* __restrict__ tp_h,
    float* __restrict__ rowmax, float* __restrict__ logit1)
{
  // layout: buf0 @0 (48K) | buf1 @49152 (48K) | PbufH @98304 (8K) |
  //         PbufL @106496 (8K) | epilogue Of @0 (128x260 f32 = 133120) |
  //         psb @133120 (1K) | mxb @134144 (1K)
  __shared__ alignas(16) char sm[135168];

  const int b    = blockIdx.y;
  const int p0   = blockIdx.x * 128;
  const int tid  = threadIdx.x;
  const int w    = tid >> 6;
  const int lane = tid & 63;
  const int l15  = lane & 15;
  const int quad = lane >> 4;
  const int swz  = l15 & 7;

  const int qt1  = w >> 2;        // GEMM1 q-tile (0/1)
  const int pt1  = (w & 3) * 2;   // GEMM1 first p-tile (0..7)
  const int dgrp = w >> 1;        // GEMM2 d-quarter (0..3)
  const int phs  = (w & 1) * 4;   // GEMM2 first p-tile (0 or 4)

  // passage B-fragments (hi/lo) for the wave's 2 p-tiles, once per block
  short8 bhi[2][8], blo[2][8];
#pragma unroll
  for (int pt = 0; pt < 2; ++pt) {
    const float* prow = pass + (((size_t)b * PP + p0 + (pt1 + pt) * 16 + l15) * DD);
#pragma unroll
    for (int c = 0; c < 8; ++c) {
      const float* p8 = prow + c * 32 + quad * 8;
      float4 x0 = *(const float4*)p8;
      float4 x1 = *(const float4*)(p8 + 4);
      float xs[8] = {x0.x, x0.y, x0.z, x0.w, x1.x, x1.y, x1.z, x1.w};
#pragma unroll
      for (int j = 0; j < 8; ++j) {
        ushort h  = bf16_rne(xs[j]);
        ushort lo = bf16_rne(xs[j] - bf16f(h));
        bhi[pt][c][j] = (short)h;
        blo[pt][c][j] = (short)lo;
      }
    }
  }

  const int gb    = (qt1 * 16 + l15) * 256;                    // ushort base into SQ
  const int vtoff = l15 * 32 + ((quad ^ ((l15 >> 1) & 3)) * 8);

  ushort* PbufH = (ushort*)(sm + 98304);
  ushort* PbufL = (ushort*)(sm + 106496);
  const int pgd  = qt1 * 2 + (quad >> 1);   // P write granule (q/8)
  const int psub = (quad & 1) * 4;          // offset within granule

  const ushort* tb = qb + (size_t)b * 32 * 24576;
  const int dma_l = w * 3072 + lane * 8;    // ushort offset in blob
  const int dma_s = w * 6144 + lane * 16;   // byte offset in LDS buffer

  floatx4 accO[4][4];   // [p-tile][d-tile]
#pragma unroll
  for (int i = 0; i < 4; ++i)
#pragma unroll
    for (int k = 0; k < 4; ++k) accO[i][k] = (floatx4){0.f, 0.f, 0.f, 0.f};
  float ps0 = 0.f, ps1 = 0.f, mx0 = -INFINITY, mx1 = -INFINITY;

  // DMA(0) -> buf0
  {
    const ushort* gs = tb + dma_l;
    char* ld = sm + dma_s;
#pragma unroll
    for (int i = 0; i < 6; ++i) gl16(gs + i * 512, ld + i * 1024);
  }
  __syncthreads();

  for (int t = 0; t < 32; ++t) {
    const char* cur = sm + (t & 1) * 49152;
    if (t < 31) {
      const ushort* gs = tb + (size_t)(t + 1) * 24576 + dma_l;
      char* ld = sm + ((t + 1) & 1) * 49152 + dma_s;
#pragma unroll
      for (int i = 0; i < 6; ++i) gl16(gs + i * 512, ld + i * 1024);
    }

    // ---- GEMM1(t): S^T(16q x 32p), 3-term split; A-frags shared by 2 B-tiles
    const ushort* Qhi = (const ushort*)cur;
    const ushort* Qlo = (const ushort*)(cur + 16384);
    floatx4 s0 = (floatx4){0.f, 0.f, 0.f, 0.f};
    floatx4 s1 = (floatx4){0.f, 0.f, 0.f, 0.f};
    __builtin_amdgcn_s_setprio(1);
#pragma unroll
    for (int c = 0; c < 8; ++c) {
      const int go = gb + (((4 * c + quad) ^ swz) << 3);
      short8 ah = *(const short8*)&Qhi[go];
      short8 al = *(const short8*)&Qlo[go];
      s0 = __builtin_amdgcn_mfma_f32_16x16x32_bf16(ah, bhi[0][c], s0, 0, 0, 0);
      s0 = __builtin_amdgcn_mfma_f32_16x16x32_bf16(ah, blo[0][c], s0, 0, 0, 0);
      s0 = __builtin_amdgcn_mfma_f32_16x16x32_bf16(al, bhi[0][c], s0, 0, 0, 0);
      s1 = __builtin_amdgcn_mfma_f32_16x16x32_bf16(ah, bhi[1][c], s1, 0, 0, 0);
      s1 = __builtin_amdgcn_mfma_f32_16x16x32_bf16(ah, blo[1][c], s1, 0, 0, 0);
      s1 = __builtin_amdgcn_mfma_f32_16x16x32_bf16(al, bhi[1][c], s1, 0, 0, 0);
    }
    __builtin_amdgcn_s_setprio(0);

    // ---- softmax(t) (fixed shift C=60, deferred reductions) + P write ----
    {
      ushort4v ph, pl;
#pragma unroll
      for (int r = 0; r < 4; ++r) {
        float s = s0[r];
        mx0 = fmaxf(mx0, s);
        float x = __expf(s - 60.f);
        ps0 += x;
        ushort h = bf16_rne(x);
        ph[r] = h;
        pl[r] = bf16_rne(x - bf16f(h));
      }
      const int wi = ((pt1 * 16 + l15) * 4 + (pgd ^ (l15 & 3))) * 8 + psub;
      *(ushort4v*)&PbufH[wi] = ph;
      *(ushort4v*)&PbufL[wi] = pl;
    }
    {
      ushort4v ph, pl;
#pragma unroll
      for (int r = 0; r < 4; ++r) {
        float s = s1[r];
        mx1 = fmaxf(mx1, s);
        float x = __expf(s - 60.f);
        ps1 += x;
        ushort h = bf16_rne(x);
        ph[r] = h;
        pl[r] = bf16_rne(x - bf16f(h));
      }
      const int wi = (((pt1 + 1) * 16 + l15) * 4 + (pgd ^ (l15 & 3))) * 8 + psub;
      *(ushort4v*)&PbufH[wi] = ph;
      *(ushort4v*)&PbufL[wi] = pl;
    }

    // producer->consumer fence for Pbuf; DMA (vmcnt) stays in flight
    asm volatile("s_waitcnt lgkmcnt(0)" ::: "memory");
    __builtin_amdgcn_s_barrier();
    __builtin_amdgcn_sched_barrier(0);

    // ---- GEMM2(t): O(64p x 64d) += P * Vhi, 2-term ----
    const ushort* TQ = (const ushort*)(cur + 32768);
    short8 vhi[4];
#pragma unroll
    for (int k = 0; k < 4; ++k)
      vhi[k] = *(const short8*)&TQ[(dgrp * 4 + k) * 512 + vtoff];
    __builtin_amdgcn_s_setprio(1);
#pragma unroll
    for (int pt = 0; pt < 4; ++pt) {
      const int ri = (((phs + pt) * 16 + l15) * 4 + (quad ^ (l15 & 3))) * 8;
      short8 phh = *(const short8*)&PbufH[ri];
      short8 pll = *(const short8*)&PbufL[ri];
#pragma unroll
      for (int k = 0; k < 4; ++k) {
        accO[pt][k] = __builtin_amdgcn_mfma_f32_16x16x32_bf16(phh, vhi[k], accO[pt][k], 0, 0, 0);
        accO[pt][k] = __builtin_amdgcn_mfma_f32_16x16x32_bf16(pll, vhi[k], accO[pt][k], 0, 0, 0);
      }
    }
    __builtin_amdgcn_s_setprio(0);
    __syncthreads();  // drain DMA(t+1); Pbuf reuse boundary
  }

  // ---- final reductions: quad-reduce, then cross-wave combine via LDS ----
  ps0 += __shfl_xor(ps0, 16); ps0 += __shfl_xor(ps0, 32);
  ps1 += __shfl_xor(ps1, 16); ps1 += __shfl_xor(ps1, 32);
  mx0 = fmaxf(mx0, __shfl_xor(mx0, 16)); mx0 = fmaxf(mx0, __shfl_xor(mx0, 32));
  mx1 = fmaxf(mx1, __shfl_xor(mx1, 16)); mx1 = fmaxf(mx1, __shfl_xor(mx1, 32));

  float* psb = (float*)(sm + 133120);  // [2 qt][8 pt][16 row]
  float* mxb = (float*)(sm + 134144);
  if (lane < 16) {
    psb[(qt1 * 8 + pt1) * 16 + l15]     = ps0;
    psb[(qt1 * 8 + pt1 + 1) * 16 + l15] = ps1;
    mxb[(qt1 * 8 + pt1) * 16 + l15]     = mx0;
    mxb[(qt1 * 8 + pt1 + 1) * 16 + l15] = mx1;
  }
  __syncthreads();
  const float pstot = psb[w * 16 + l15] + psb[128 + w * 16 + l15];
  const float mxtot = fmaxf(mxb[w * 16 + l15], mxb[128 + w * 16 + l15]);
  const size_t rowoff = (size_t)b * PP + p0 + w * 16;
  if (lane < 16) rowmax[rowoff + lane] = mxtot;

  // ---- stage O to full-block scratch (rows x 260 f32) ----
  float* Of = (float*)sm;
#pragma unroll
  for (int pt = 0; pt < 4; ++pt)
#pragma unroll
    for (int k = 0; k < 4; ++k)
#pragma unroll
      for (int r = 0; r < 4; ++r)
        Of[((w & 1) * 64 + pt * 16 + quad * 4 + r) * 260 + dgrp * 64 + k * 16 + l15] =
            accO[pt][k][r];
  __syncthreads();

  // ---- row pass: normalize, tanh-fuse, store halves, logit1 dot ----
  const float4 w1 = *(const float4*)(w_attn + lane * 4);
#pragma unroll
  for (int j = 0; j < 16; ++j) {
    float4 o = *(const float4*)&Of[(w * 16 + j) * 260 + lane * 4];
    float linv = 1.f / __shfl(pstot, j);
    float4 pv4 = *(const float4*)(pass + (rowoff + j) * DD + lane * 4);
    float tpx = ftanh(pv4.x), tpy = ftanh(pv4.y), tpz = ftanh(pv4.z), tpw = ftanh(pv4.w);
    float4 f;
    f.x = tpx * ftanh(o.x * linv);
    f.y = tpy * ftanh(o.y * linv);
    f.z = tpz * ftanh(o.z * linv);
    f.w = tpw * ftanh(o.w * linv);
    half4 fh = {(_Float16)f.x, (_Float16)f.y, (_Float16)f.z, (_Float16)f.w};
    half4 th = {(_Float16)tpx, (_Float16)tpy, (_Float16)tpz, (_Float16)tpw};
    *(half4*)(first_h + (rowoff + j) * DD + lane * 4) = fh;
    *(half4*)(tp_h + (rowoff + j) * DD + lane * 4) = th;
    float part = f.x * w1.x + f.y * w1.y + f.z * w1.z + f.w * w1.w;
    part += __shfl_xor(part, 1);  part += __shfl_xor(part, 2);
    part += __shfl_xor(part, 4);  part += __shfl_xor(part, 8);
    part += __shfl_xor(part, 16); part += __shfl_xor(part, 32);
    if (lane == 0) logit1[rowoff + j] = part;
  }
}

// ---------------------------------------------------------------------------
// kB2: q2c partials with unnormalized weights e^{rowmax-60}. No atomics.
// ---------------------------------------------------------------------------
__global__ __launch_bounds__(256) void kB2(
    const float* __restrict__ pass, const float* __restrict__ rowmax,
    float* __restrict__ numpart, float* __restrict__ denpart)
{
  const int b = blockIdx.y, chunk = blockIdx.x;   // 32 chunks x 128 p
  const int tid = threadIdx.x, r = tid >> 6, ln = tid & 63;
  __shared__ float sacc[4][64][4];
  __shared__ float sden[4][64];
  const float* rm = rowmax + (size_t)b * PP + chunk * 128;
  const float* pb = pass + ((size_t)b * PP + chunk * 128) * DD;
  float4 acc = make_float4(0.f, 0.f, 0.f, 0.f);
  float den = 0.f;
  for (int p = r; p < 128; p += 4) {
    float wgt = __expf(rm[p] - 60.f);
    float4 v = *(const float4*)(pb + (size_t)p * DD + ln * 4);
    acc.x += wgt * v.x; acc.y += wgt * v.y;
    acc.z += wgt * v.z; acc.w += wgt * v.w;
    den += wgt;
  }
  *(float4*)&sacc[r][ln][0] = acc;
  sden[r][ln] = den;
  __syncthreads();
  if (r == 0) {
    float4 s;
    s.x = sacc[0][ln][0] + sacc[1][ln][0] + sacc[2][ln][0] + sacc[3][ln][0];
    s.y = sacc[0][ln][1] + sacc[1][ln][1] + sacc[2][ln][1] + sacc[3][ln][1];
    s.z = sacc[0][ln][2] + sacc[1][ln][2] + sacc[2][ln][2] + sacc[3][ln][2];
    s.w = sacc[0][ln][3] + sacc[1][ln][3] + sacc[2][ln][3] + sacc[3][ln][3];
    *(float4*)(numpart + (size_t)(chunk * 16 + b) * DD + ln * 4) = s;
    if (ln == 0)
      denpart[chunk * 16 + b] = sden[0][0] + sden[1][0] + sden[2][0] + sden[3][0];
  }
}

// kB3: reduce partials -> q2c -> tq, w2tq
__global__ void kB3(const float* __restrict__ numpart, const float* __restrict__ denpart,
                    const float* __restrict__ w_attn,
                    float* __restrict__ tq, float* __restrict__ w2tq)
{
  const int b = blockIdx.x, d = threadIdx.x;
  float den = 0.f, num = 0.f;
#pragma unroll
  for (int c = 0; c < 32; ++c) {
    den += denpart[c * 16 + b];
    num += numpart[(size_t)(c * 16 + b) * DD + d];
  }
  float t = ftanh(num / den);
  tq[b * DD + d] = t;
  w2tq[b * DD + d] = w_attn[DD + d] * t;
}

// kC: el[p] = exp(logit1 + dot(tp, w2tq))   (unnormalized logit weight)
__global__ __launch_bounds__(256) void kC(
    const _Float16* __restrict__ tp_h, const float* __restrict__ logit1,
    const float* __restrict__ w2tq, float* __restrict__ el)
{
  const int b = blockIdx.y, chunk = blockIdx.x;  // 32 chunks x 128 p
  const int wave = threadIdx.x >> 6, lane = threadIdx.x & 63;
  const float4 wv = *(const float4*)(w2tq + b * DD + (lane << 2));
  const int pbase = chunk * 128 + wave * 32;
  for (int j = 0; j < 32; ++j) {
    int p = pbase + j;
    half4 tv = *(const half4*)(tp_h + ((size_t)b * PP + p) * DD + (lane << 2));
    float part = (float)tv.x * wv.x + (float)tv.y * wv.y +
                 (float)tv.z * wv.z + (float)tv.w * wv.w;
    part += __shfl_xor(part, 1);  part += __shfl_xor(part, 2);
    part += __shfl_xor(part, 4);  part += __shfl_xor(part, 8);
    part += __shfl_xor(part, 16); part += __shfl_xor(part, 32);
    if (lane == 0)
      el[(size_t)b * PP + p] = __expf(logit1[(size_t)b * PP + p] + part);
  }
}

// kE: reducer partials (no atomics, half4 vector loads)
__global__ __launch_bounds__(256) void kE(
    const _Float16* __restrict__ tp_h, const _Float16* __restrict__ first_h,
    const float* __restrict__ el,
    float* __restrict__ r1part, float* __restrict__ r2part, float* __restrict__ den2part)
{
  const int b = blockIdx.y, chunk = blockIdx.x;   // 32 chunks x 128 p
  const int tid = threadIdx.x, r = tid >> 6, ln = tid & 63;
  __shared__ float s1[4][64][4];
  __shared__ float s2[4][64][4];
  __shared__ float sd[4][64];
  const float* ev = el + (size_t)b * PP + chunk * 128;
  const size_t base = ((size_t)b * PP + chunk * 128) * DD;
  float a1[4] = {0.f, 0.f, 0.f, 0.f}, a2[4] = {0.f, 0.f, 0.f, 0.f};
  float den = 0.f;
  for (int p = r; p < 128; p += 4) {
    float wgt = ev[p];
    half4 f = *(const half4*)(first_h + base + (size_t)p * DD + ln * 4);
    half4 t = *(const half4*)(tp_h + base + (size_t)p * DD + ln * 4);
    a1[0] += wgt * (float)f.x; a1[1] += wgt * (float)f.y;
    a1[2] += wgt * (float)f.z; a1[3] += wgt * (float)f.w;
    a2[0] += wgt * (float)t.x; a2[1] += wgt * (float)t.y;
    a2[2] += wgt * (float)t.z; a2[3] += wgt * (float)t.w;
    den += wgt;
  }
  *(float4*)&s1[r][ln][0] = *(float4*)a1;
  *(float4*)&s2[r][ln][0] = *(float4*)a2;
  sd[r][ln] = den;
  __syncthreads();
  if (r == 0) {
    float o1[4], o2[4];
#pragma unroll
    for (int i = 0; i < 4; ++i) {
      o1[i] = s1[0][ln][i] + s1[1][ln][i] + s1[2][ln][i] + s1[3][ln][i];
      o2[i] = s2[0][ln][i] + s2[1][ln][i] + s2[2][ln][i] + s2[3][ln][i];
    }
    *(float4*)(r1part + (size_t)(chunk * 16 + b) * DD + ln * 4) = *(float4*)o1;
    *(float4*)(r2part + (size_t)(chunk * 16 + b) * DD + ln * 4) = *(float4*)o2;
    if (ln == 0)
      den2part[chunk * 16 + b] = sd[0][0] + sd[1][0] + sd[2][0] + sd[3][0];
  }
}

// kF: reduce partials, normalize, output GEMM
__global__ __launch_bounds__(256) void kF(
    const float* __restrict__ r1part, const float* __restrict__ r2part,
    const float* __restrict__ den2part, const float* __restrict__ tq,
    const float* __restrict__ w_out, const float* __restrict__ b_out,
    float* __restrict__ out)
{
  const int b = blockIdx.x, o = threadIdx.x;
  __shared__ float R1[256], R2[256];
  float den = 0.f, red1 = 0.f, red2 = 0.f;
#pragma unroll
  for (int c = 0; c < 32; ++c) {
    den += den2part[c * 16 + b];
    red1 += r1part[(size_t)(c * 16 + b) * DD + o];
    red2 += r2part[(size_t)(c * 16 + b) * DD + o];
  }
  float inv = 1.f / den;
  R1[o] = red1 * inv;
  R2[o] = red2 * inv * tq[b * DD + o];
  __syncthreads();
  float acc = b_out[o];
  for (int k = 0; k < DD; ++k)
    acc += R1[k] * w_out[k * 256 + o];
  for (int k = 0; k < DD; ++k)
    acc += R2[k] * w_out[(DD + k) * 256 + o];
  out[b * 256 + o] = acc;
}

extern "C" void kernel_launch(void* const* d_in, const int* in_sizes, int n_in,
                              void* d_out, int out_size, void* d_ws, size_t ws_size,
                              hipStream_t stream) {
  const float* pass   = (const float*)d_in[0];
  const float* ques   = (const float*)d_in[1];
  const float* w_attn = (const float*)d_in[2];
  // d_in[3] = b_attn: uniform softmax shift, cancels in num/den -> dropped
  const float* w_out  = (const float*)d_in[4];
  const float* b_out  = (const float*)d_in[5];
  float* out = (float*)d_out;

  float* ws       = (float*)d_ws;
  float* rowmax   = ws;                                   // BB*PP
  float* logit1   = rowmax   + (size_t)BB * PP;           // BB*PP
  float* el       = logit1   + (size_t)BB * PP;           // BB*PP
  float* numpart  = el       + (size_t)BB * PP;           // 32*BB*DD
  float* denpart  = numpart  + (size_t)32 * BB * DD;      // 32*BB
  float* r1part   = denpart  + 32 * BB;                   // 32*BB*DD
  float* r2part   = r1part   + (size_t)32 * BB * DD;      // 32*BB*DD
  float* den2part = r2part   + (size_t)32 * BB * DD;      // 32*BB
  float* tq       = den2part + 32 * BB;                   // BB*DD
  float* w2tq     = tq       + BB * DD;                   // BB*DD
  ushort* qbb     = (ushort*)(w2tq + BB * DD);            // BB*32*24576 ushorts
  _Float16* first_h = (_Float16*)(qbb + (size_t)BB * 32 * 24576);
  _Float16* tp_h    = first_h + (size_t)BB * PP * DD;

  kQprep<<<dim3(QQ / 32, BB), 256, 0, stream>>>(ques, qbb);
  kA    <<<dim3(PP / 128, BB), 512, 0, stream>>>(pass, qbb, w_attn,
                                                 first_h, tp_h, rowmax, logit1);
  kB2   <<<dim3(32, BB), 256, 0, stream>>>(pass, rowmax, numpart, denpart);
  kB3   <<<BB, 256, 0, stream>>>(numpart, denpart, w_attn, tq, w2tq);
  kC    <<<dim3(32, BB), 256, 0, stream>>>(tp_h, logit1, w2tq, el);
  kE    <<<dim3(32, BB), 256, 0, stream>>>(tp_h, first_h, el, r1part, r2part, den2part);
  kF    <<<BB, 256, 0, stream>>>(r1part, r2part, den2part, tq, w_out, b_out, out);
}

// Round 2
// 378.870 us; speedup vs baseline: 1.0059x; 1.0059x over previous
//
#include <hip/hip_runtime.h>
#include <cmath>

#define BB 16
#define PP 4096
#define QQ 1024
#define DD 256

typedef __attribute__((ext_vector_type(8))) short short8;
typedef __attribute__((ext_vector_type(4))) float floatx4;
typedef __attribute__((ext_vector_type(4))) _Float16 half4;
typedef __attribute__((ext_vector_type(4))) unsigned short ushort4v;

static __device__ inline ushort bf16_rne(float x) {
  unsigned u = __float_as_uint(x);
  unsigned r = (u + 0x7fffu + ((u >> 16) & 1u)) >> 16;
  return (ushort)r;
}
static __device__ inline float bf16f(ushort h) { return __uint_as_float(((unsigned)h) << 16); }

static __device__ inline float ftanh(float x) {
  float e = __expf(2.0f * x);
  return 1.0f - 2.0f * __builtin_amdgcn_rcpf(e + 1.0f);
}

static __device__ inline void gl16(const void* g, void* l) {
  __builtin_amdgcn_global_load_lds(
      (const __attribute__((address_space(1))) unsigned int*)g,
      (__attribute__((address_space(3))) unsigned int*)l, 16, 0, 0);
}

// ---------------------------------------------------------------------------
// kQprep: Q -> per-(b,32q-tile) 48KB blobs: [SQhi 16K | SQlo 16K | TQhi 16K].
//  SQ: row-major hi/lo, granule j of row r at slot j^(r&7).
//  TQ: transposed [d][32q] bf16-hi only, granule k at slot k^((d>>1)&3).
// ---------------------------------------------------------------------------
__global__ __launch_bounds__(256) void kQprep(
    const float* __restrict__ ques, ushort* __restrict__ qb)
{
  const int b = blockIdx.y, qt = blockIdx.x;
  __shared__ float tile[32][260];
  const int tid = threadIdx.x;
  const float* src = ques + ((size_t)b * QQ + qt * 32) * DD;
  for (int i = tid; i < 32 * 64; i += 256) {
    int r = i >> 6, c = (i & 63) << 2;
    *(float4*)&tile[r][c] = *(const float4*)(src + r * DD + c);
  }
  __syncthreads();
  ushort* blob = qb + (size_t)(b * 32 + qt) * 24576;
  {
    int r = tid >> 3;
    int j0 = (tid & 7) * 4;
#pragma unroll
    for (int jj = 0; jj < 4; ++jj) {
      int j = j0 + jj;
      ushort h8[8], l8[8];
#pragma unroll
      for (int e = 0; e < 8; ++e) {
        float x = tile[r][j * 8 + e];
        ushort h = bf16_rne(x);
        h8[e] = h; l8[e] = bf16_rne(x - bf16f(h));
      }
      int g = r * 32 + (j ^ (r & 7));
      *(uint4*)&blob[(size_t)g * 8] = *(uint4*)h8;
      *(uint4*)&blob[8192 + (size_t)g * 8] = *(uint4*)l8;
    }
  }
  {
    int d = tid;
    int s = (d >> 1) & 3;
    ushort h32[32];
#pragma unroll
    for (int r = 0; r < 32; ++r) h32[r] = bf16_rne(tile[r][d]);
#pragma unroll
    for (int k = 0; k < 4; ++k)
      *(uint4*)&blob[16384 + (size_t)d * 32 + (k ^ s) * 8] = *(uint4*)&h32[k * 8];
  }
}

// ---------------------------------------------------------------------------
// kA: flash attention, LDS-traffic-minimized wave decomposition.
// 512 thr = 8 waves. Double-buffered 48KB Q tiles + 16KB split-hi/lo P buffer.
// GEMM1: wave = 1 q-tile x 2 p-tiles (A-frags read once, used for 2 B-tiles).
// GEMM2: wave = 4 p-tiles x 4 d-tiles (64p x 64d); P transits LDS (hi/lo split
//        so reads are direct short8 A-frags, no unpack).
// Per iter: DMA(t+1) | GEMM1(t) | softmax(t) | P-write | lgkm-barrier |
//           GEMM2(t) | syncthreads.  vmcnt NOT drained at mid-barrier.
// Register budget: LDS (132KB) forces 1 block/CU = 2 waves/SIMD, so the
// allocator may use 256 VGPR/thread — pinned via amdgpu_waves_per_eu(2,2).
// Live set ~230 (B-frags 128 + accO 64 + temps): fits, no spill.
// ---------------------------------------------------------------------------
__global__ __attribute__((amdgpu_flat_work_group_size(512, 512), amdgpu_waves_per_eu(2, 2)))
void kA(
    const float* __restrict__ pass, const ushort* __restrict__ qb,
    const float* __restrict__ w_attn,
    _Float16* __restrict__ first_h, _Float16* __restrict__ tp_h,
    float* __restrict__ rowmax, float* __restrict__ logit1)
{
  // layout: buf0 @0 (48K) | buf1 @49152 (48K) | PbufH @98304 (8K) |
  //         PbufL @106496 (8K) | epilogue Of @0 (128x260 f32 = 133120) |
  //         psb @133120 (1K) | mxb @134144 (1K)
  __shared__ alignas(16) char sm[135168];

  const int b    = blockIdx.y;
  const int p0   = blockIdx.x * 128;
  const int tid  = threadIdx.x;
  const int w    = tid >> 6;
  const int lane = tid & 63;
  const int l15  = lane & 15;
  const int quad = lane >> 4;
  const int swz  = l15 & 7;

  const int qt1  = w >> 2;        // GEMM1 q-tile (0/1)
  const int pt1  = (w & 3) * 2;   // GEMM1 first p-tile (0..7)
  const int dgrp = w >> 1;        // GEMM2 d-quarter (0..3)
  const int phs  = (w & 1) * 4;   // GEMM2 first p-tile (0 or 4)

  // passage B-fragments (hi/lo) for the wave's 2 p-tiles, once per block
  short8 bhi[2][8], blo[2][8];
#pragma unroll
  for (int pt = 0; pt < 2; ++pt) {
    const float* prow = pass + (((size_t)b * PP + p0 + (pt1 + pt) * 16 + l15) * DD);
#pragma unroll
    for (int c = 0; c < 8; ++c) {
      const float* p8 = prow + c * 32 + quad * 8;
      float4 x0 = *(const float4*)p8;
      float4 x1 = *(const float4*)(p8 + 4);
      float xs[8] = {x0.x, x0.y, x0.z, x0.w, x1.x, x1.y, x1.z, x1.w};
#pragma unroll
      for (int j = 0; j < 8; ++j) {
        ushort h  = bf16_rne(xs[j]);
        ushort lo = bf16_rne(xs[j] - bf16f(h));
        bhi[pt][c][j] = (short)h;
        blo[pt][c][j] = (short)lo;
      }
    }
  }

  const int gb    = (qt1 * 16 + l15) * 256;                    // ushort base into SQ
  const int vtoff = l15 * 32 + ((quad ^ ((l15 >> 1) & 3)) * 8);

  ushort* PbufH = (ushort*)(sm + 98304);
  ushort* PbufL = (ushort*)(sm + 106496);
  const int pgd  = qt1 * 2 + (quad >> 1);   // P write granule (q/8)
  const int psub = (quad & 1) * 4;          // offset within granule

  const ushort* tb = qb + (size_t)b * 32 * 24576;
  const int dma_l = w * 3072 + lane * 8;    // ushort offset in blob
  const int dma_s = w * 6144 + lane * 16;   // byte offset in LDS buffer

  floatx4 accO[4][4];   // [p-tile][d-tile]
#pragma unroll
  for (int i = 0; i < 4; ++i)
#pragma unroll
    for (int k = 0; k < 4; ++k) accO[i][k] = (floatx4){0.f, 0.f, 0.f, 0.f};
  float ps0 = 0.f, ps1 = 0.f, mx0 = -INFINITY, mx1 = -INFINITY;

  // DMA(0) -> buf0
  {
    const ushort* gs = tb + dma_l;
    char* ld = sm + dma_s;
#pragma unroll
    for (int i = 0; i < 6; ++i) gl16(gs + i * 512, ld + i * 1024);
  }
  __syncthreads();

  for (int t = 0; t < 32; ++t) {
    const char* cur = sm + (t & 1) * 49152;
    if (t < 31) {
      const ushort* gs = tb + (size_t)(t + 1) * 24576 + dma_l;
      char* ld = sm + ((t + 1) & 1) * 49152 + dma_s;
#pragma unroll
      for (int i = 0; i < 6; ++i) gl16(gs + i * 512, ld + i * 1024);
    }

    // ---- GEMM1(t): S^T(16q x 32p), 3-term split; A-frags shared by 2 B-tiles
    const ushort* Qhi = (const ushort*)cur;
    const ushort* Qlo = (const ushort*)(cur + 16384);
    floatx4 s0 = (floatx4){0.f, 0.f, 0.f, 0.f};
    floatx4 s1 = (floatx4){0.f, 0.f, 0.f, 0.f};
    __builtin_amdgcn_s_setprio(1);
#pragma unroll
    for (int c = 0; c < 8; ++c) {
      const int go = gb + (((4 * c + quad) ^ swz) << 3);
      short8 ah = *(const short8*)&Qhi[go];
      short8 al = *(const short8*)&Qlo[go];
      s0 = __builtin_amdgcn_mfma_f32_16x16x32_bf16(ah, bhi[0][c], s0, 0, 0, 0);
      s0 = __builtin_amdgcn_mfma_f32_16x16x32_bf16(ah, blo[0][c], s0, 0, 0, 0);
      s0 = __builtin_amdgcn_mfma_f32_16x16x32_bf16(al, bhi[0][c], s0, 0, 0, 0);
      s1 = __builtin_amdgcn_mfma_f32_16x16x32_bf16(ah, bhi[1][c], s1, 0, 0, 0);
      s1 = __builtin_amdgcn_mfma_f32_16x16x32_bf16(ah, blo[1][c], s1, 0, 0, 0);
      s1 = __builtin_amdgcn_mfma_f32_16x16x32_bf16(al, bhi[1][c], s1, 0, 0, 0);
    }
    __builtin_amdgcn_s_setprio(0);

    // ---- softmax(t) (fixed shift C=60, deferred reductions) + P write ----
    {
      ushort4v ph, pl;
#pragma unroll
      for (int r = 0; r < 4; ++r) {
        float s = s0[r];
        mx0 = fmaxf(mx0, s);
        float x = __expf(s - 60.f);
        ps0 += x;
        ushort h = bf16_rne(x);
        ph[r] = h;
        pl[r] = bf16_rne(x - bf16f(h));
      }
      const int wi = ((pt1 * 16 + l15) * 4 + (pgd ^ (l15 & 3))) * 8 + psub;
      *(ushort4v*)&PbufH[wi] = ph;
      *(ushort4v*)&PbufL[wi] = pl;
    }
    {
      ushort4v ph, pl;
#pragma unroll
      for (int r = 0; r < 4; ++r) {
        float s = s1[r];
        mx1 = fmaxf(mx1, s);
        float x = __expf(s - 60.f);
        ps1 += x;
        ushort h = bf16_rne(x);
        ph[r] = h;
        pl[r] = bf16_rne(x - bf16f(h));
      }
      const int wi = (((pt1 + 1) * 16 + l15) * 4 + (pgd ^ (l15 & 3))) * 8 + psub;
      *(ushort4v*)&PbufH[wi] = ph;
      *(ushort4v*)&PbufL[wi] = pl;
    }

    // producer->consumer fence for Pbuf; DMA (vmcnt) stays in flight
    asm volatile("s_waitcnt lgkmcnt(0)" ::: "memory");
    __builtin_amdgcn_s_barrier();
    __builtin_amdgcn_sched_barrier(0);

    // ---- GEMM2(t): O(64p x 64d) += P * Vhi, 2-term ----
    const ushort* TQ = (const ushort*)(cur + 32768);
    short8 vhi[4];
#pragma unroll
    for (int k = 0; k < 4; ++k)
      vhi[k] = *(const short8*)&TQ[(dgrp * 4 + k) * 512 + vtoff];
    __builtin_amdgcn_s_setprio(1);
#pragma unroll
    for (int pt = 0; pt < 4; ++pt) {
      const int ri = (((phs + pt) * 16 + l15) * 4 + (quad ^ (l15 & 3))) * 8;
      short8 phh = *(const short8*)&PbufH[ri];
      short8 pll = *(const short8*)&PbufL[ri];
#pragma unroll
      for (int k = 0; k < 4; ++k) {
        accO[pt][k] = __builtin_amdgcn_mfma_f32_16x16x32_bf16(phh, vhi[k], accO[pt][k], 0, 0, 0);
        accO[pt][k] = __builtin_amdgcn_mfma_f32_16x16x32_bf16(pll, vhi[k], accO[pt][k], 0, 0, 0);
      }
    }
    __builtin_amdgcn_s_setprio(0);
    __syncthreads();  // drain DMA(t+1); Pbuf reuse boundary
  }

  // ---- final reductions: quad-reduce, then cross-wave combine via LDS ----
  ps0 += __shfl_xor(ps0, 16); ps0 += __shfl_xor(ps0, 32);
  ps1 += __shfl_xor(ps1, 16); ps1 += __shfl_xor(ps1, 32);
  mx0 = fmaxf(mx0, __shfl_xor(mx0, 16)); mx0 = fmaxf(mx0, __shfl_xor(mx0, 32));
  mx1 = fmaxf(mx1, __shfl_xor(mx1, 16)); mx1 = fmaxf(mx1, __shfl_xor(mx1, 32));

  float* psb = (float*)(sm + 133120);  // [2 qt][8 pt][16 row]
  float* mxb = (float*)(sm + 134144);
  if (lane < 16) {
    psb[(qt1 * 8 + pt1) * 16 + l15]     = ps0;
    psb[(qt1 * 8 + pt1 + 1) * 16 + l15] = ps1;
    mxb[(qt1 * 8 + pt1) * 16 + l15]     = mx0;
    mxb[(qt1 * 8 + pt1 + 1) * 16 + l15] = mx1;
  }
  __syncthreads();
  const float pstot = psb[w * 16 + l15] + psb[128 + w * 16 + l15];
  const float mxtot = fmaxf(mxb[w * 16 + l15], mxb[128 + w * 16 + l15]);
  const size_t rowoff = (size_t)b * PP + p0 + w * 16;
  if (lane < 16) rowmax[rowoff + lane] = mxtot;

  // ---- stage O to full-block scratch (rows x 260 f32) ----
  float* Of = (float*)sm;
#pragma unroll
  for (int pt = 0; pt < 4; ++pt)
#pragma unroll
    for (int k = 0; k < 4; ++k)
#pragma unroll
      for (int r = 0; r < 4; ++r)
        Of[((w & 1) * 64 + pt * 16 + quad * 4 + r) * 260 + dgrp * 64 + k * 16 + l15] =
            accO[pt][k][r];
  __syncthreads();

  // ---- row pass: normalize, tanh-fuse, store halves, logit1 dot ----
  const float4 w1 = *(const float4*)(w_attn + lane * 4);
#pragma unroll
  for (int j = 0; j < 16; ++j) {
    float4 o = *(const float4*)&Of[(w * 16 + j) * 260 + lane * 4];
    float linv = 1.f / __shfl(pstot, j);
    float4 pv4 = *(const float4*)(pass + (rowoff + j) * DD + lane * 4);
    float tpx = ftanh(pv4.x), tpy = ftanh(pv4.y), tpz = ftanh(pv4.z), tpw = ftanh(pv4.w);
    float4 f;
    f.x = tpx * ftanh(o.x * linv);
    f.y = tpy * ftanh(o.y * linv);
    f.z = tpz * ftanh(o.z * linv);
    f.w = tpw * ftanh(o.w * linv);
    half4 fh = {(_Float16)f.x, (_Float16)f.y, (_Float16)f.z, (_Float16)f.w};
    half4 th = {(_Float16)tpx, (_Float16)tpy, (_Float16)tpz, (_Float16)tpw};
    *(half4*)(first_h + (rowoff + j) * DD + lane * 4) = fh;
    *(half4*)(tp_h + (rowoff + j) * DD + lane * 4) = th;
    float part = f.x * w1.x + f.y * w1.y + f.z * w1.z + f.w * w1.w;
    part += __shfl_xor(part, 1);  part += __shfl_xor(part, 2);
    part += __shfl_xor(part, 4);  part += __shfl_xor(part, 8);
    part += __shfl_xor(part, 16); part += __shfl_xor(part, 32);
    if (lane == 0) logit1[rowoff + j] = part;
  }
}

// ---------------------------------------------------------------------------
// kB2: q2c partials with unnormalized weights e^{rowmax-60}. No atomics.
// ---------------------------------------------------------------------------
__global__ __launch_bounds__(256) void kB2(
    const float* __restrict__ pass, const float* __restrict__ rowmax,
    float* __restrict__ numpart, float* __restrict__ denpart)
{
  const int b = blockIdx.y, chunk = blockIdx.x;   // 32 chunks x 128 p
  const int tid = threadIdx.x, r = tid >> 6, ln = tid & 63;
  __shared__ float sacc[4][64][4];
  __shared__ float sden[4][64];
  const float* rm = rowmax + (size_t)b * PP + chunk * 128;
  const float* pb = pass + ((size_t)b * PP + chunk * 128) * DD;
  float4 acc = make_float4(0.f, 0.f, 0.f, 0.f);
  float den = 0.f;
  for (int p = r; p < 128; p += 4) {
    float wgt = __expf(rm[p] - 60.f);
    float4 v = *(const float4*)(pb + (size_t)p * DD + ln * 4);
    acc.x += wgt * v.x; acc.y += wgt * v.y;
    acc.z += wgt * v.z; acc.w += wgt * v.w;
    den += wgt;
  }
  *(float4*)&sacc[r][ln][0] = acc;
  sden[r][ln] = den;
  __syncthreads();
  if (r == 0) {
    float4 s;
    s.x = sacc[0][ln][0] + sacc[1][ln][0] + sacc[2][ln][0] + sacc[3][ln][0];
    s.y = sacc[0][ln][1] + sacc[1][ln][1] + sacc[2][ln][1] + sacc[3][ln][1];
    s.z = sacc[0][ln][2] + sacc[1][ln][2] + sacc[2][ln][2] + sacc[3][ln][2];
    s.w = sacc[0][ln][3] + sacc[1][ln][3] + sacc[2][ln][3] + sacc[3][ln][3];
    *(float4*)(numpart + (size_t)(chunk * 16 + b) * DD + ln * 4) = s;
    if (ln == 0)
      denpart[chunk * 16 + b] = sden[0][0] + sden[1][0] + sden[2][0] + sden[3][0];
  }
}

// kB3: reduce partials -> q2c -> tq, w2tq
__global__ void kB3(const float* __restrict__ numpart, const float* __restrict__ denpart,
                    const float* __restrict__ w_attn,
                    float* __restrict__ tq, float* __restrict__ w2tq)
{
  const int b = blockIdx.x, d = threadIdx.x;
  float den = 0.f, num = 0.f;
#pragma unroll
  for (int c = 0; c < 32; ++c) {
    den += denpart[c * 16 + b];
    num += numpart[(size_t)(c * 16 + b) * DD + d];
  }
  float t = ftanh(num / den);
  tq[b * DD + d] = t;
  w2tq[b * DD + d] = w_attn[DD + d] * t;
}

// kC: el[p] = exp(logit1 + dot(tp, w2tq))   (unnormalized logit weight)
__global__ __launch_bounds__(256) void kC(
    const _Float16* __restrict__ tp_h, const float* __restrict__ logit1,
    const float* __restrict__ w2tq, float* __restrict__ el)
{
  const int b = blockIdx.y, chunk = blockIdx.x;  // 32 chunks x 128 p
  const int wave = threadIdx.x >> 6, lane = threadIdx.x & 63;
  const float4 wv = *(const float4*)(w2tq + b * DD + (lane << 2));
  const int pbase = chunk * 128 + wave * 32;
  for (int j = 0; j < 32; ++j) {
    int p = pbase + j;
    half4 tv = *(const half4*)(tp_h + ((size_t)b * PP + p) * DD + (lane << 2));
    float part = (float)tv.x * wv.x + (float)tv.y * wv.y +
                 (float)tv.z * wv.z + (float)tv.w * wv.w;
    part += __shfl_xor(part, 1);  part += __shfl_xor(part, 2);
    part += __shfl_xor(part, 4);  part += __shfl_xor(part, 8);
    part += __shfl_xor(part, 16); part += __shfl_xor(part, 32);
    if (lane == 0)
      el[(size_t)b * PP + p] = __expf(logit1[(size_t)b * PP + p] + part);
  }
}

// kE: reducer partials (no atomics, half4 vector loads)
__global__ __launch_bounds__(256) void kE(
    const _Float16* __restrict__ tp_h, const _Float16* __restrict__ first_h,
    const float* __restrict__ el,
    float* __restrict__ r1part, float* __restrict__ r2part, float* __restrict__ den2part)
{
  const int b = blockIdx.y, chunk = blockIdx.x;   // 32 chunks x 128 p
  const int tid = threadIdx.x, r = tid >> 6, ln = tid & 63;
  __shared__ float s1[4][64][4];
  __shared__ float s2[4][64][4];
  __shared__ float sd[4][64];
  const float* ev = el + (size_t)b * PP + chunk * 128;
  const size_t base = ((size_t)b * PP + chunk * 128) * DD;
  float a1[4] = {0.f, 0.f, 0.f, 0.f}, a2[4] = {0.f, 0.f, 0.f, 0.f};
  float den = 0.f;
  for (int p = r; p < 128; p += 4) {
    float wgt = ev[p];
    half4 f = *(const half4*)(first_h + base + (size_t)p * DD + ln * 4);
    half4 t = *(const half4*)(tp_h + base + (size_t)p * DD + ln * 4);
    a1[0] += wgt * (float)f.x; a1[1] += wgt * (float)f.y;
    a1[2] += wgt * (float)f.z; a1[3] += wgt * (float)f.w;
    a2[0] += wgt * (float)t.x; a2[1] += wgt * (float)t.y;
    a2[2] += wgt * (float)t.z; a2[3] += wgt * (float)t.w;
    den += wgt;
  }
  *(float4*)&s1[r][ln][0] = *(float4*)a1;
  *(float4*)&s2[r][ln][0] = *(float4*)a2;
  sd[r][ln] = den;
  __syncthreads();
  if (r == 0) {
    float o1[4], o2[4];
#pragma unroll
    for (int i = 0; i < 4; ++i) {
      o1[i] = s1[0][ln][i] + s1[1][ln][i] + s1[2][ln][i] + s1[3][ln][i];
      o2[i] = s2[0][ln][i] + s2[1][ln][i] + s2[2][ln][i] + s2[3][ln][i];
    }
    *(float4*)(r1part + (size_t)(chunk * 16 + b) * DD + ln * 4) = *(float4*)o1;
    *(float4*)(r2part + (size_t)(chunk * 16 + b) * DD + ln * 4) = *(float4*)o2;
    if (ln == 0)
      den2part[chunk * 16 + b] = sd[0][0] + sd[1][0] + sd[2][0] + sd[3][0];
  }
}

// kF: reduce partials, normalize, output GEMM
__global__ __launch_bounds__(256) void kF(
    const float* __restrict__ r1part, const float* __restrict__ r2part,
    const float* __restrict__ den2part, const float* __restrict__ tq,
    const float* __restrict__ w_out, const float* __restrict__ b_out,
    float* __restrict__ out)
{
  const int b = blockIdx.x, o = threadIdx.x;
  __shared__ float R1[256], R2[256];
  float den = 0.f, red1 = 0.f, red2 = 0.f;
#pragma unroll
  for (int c = 0; c < 32; ++c) {
    den += den2part[c * 16 + b];
    red1 += r1part[(size_t)(c * 16 + b) * DD + o];
    red2 += r2part[(size_t)(c * 16 + b) * DD + o];
  }
  float inv = 1.f / den;
  R1[o] = red1 * inv;
  R2[o] = red2 * inv * tq[b * DD + o];
  __syncthreads();
  float acc = b_out[o];
  for (int k = 0; k < DD; ++k)
    acc += R1[k] * w_out[k * 256 + o];
  for (int k = 0; k < DD; ++k)
    acc += R2[k] * w_out[(DD + k) * 256 + o];
  out[b * 256 + o] = acc;
}

extern "C" void kernel_launch(void* const* d_in, const int* in_sizes, int n_in,
                              void* d_out, int out_size, void* d_ws, size_t ws_size,
                              hipStream_t stream) {
  const float* pass   = (const float*)d_in[0];
  const float* ques   = (const float*)d_in[1];
  const float* w_attn = (const float*)d_in[2];
  // d_in[3] = b_attn: uniform softmax shift, cancels in num/den -> dropped
  const float* w_out  = (const float*)d_in[4];
  const float* b_out  = (const float*)d_in[5];
  float* out = (float*)d_out;

  float* ws       = (float*)d_ws;
  float* rowmax   = ws;                                   // BB*PP
  float* logit1   = rowmax   + (size_t)BB * PP;           // BB*PP
  float* el       = logit1   + (size_t)BB * PP;           // BB*PP
  float* numpart  = el       + (size_t)BB * PP;           // 32*BB*DD
  float* denpart  = numpart  + (size_t)32 * BB * DD;      // 32*BB
  float* r1part   = denpart  + 32 * BB;                   // 32*BB*DD
  float* r2part   = r1part   + (size_t)32 * BB * DD;      // 32*BB*DD
  float* den2part = r2part   + (size_t)32 * BB * DD;      // 32*BB
  float* tq       = den2part + 32 * BB;                   // BB*DD
  float* w2tq     = tq       + BB * DD;                   // BB*DD
  ushort* qbb     = (ushort*)(w2tq + BB * DD);            // BB*32*24576 ushorts
  _Float16* first_h = (_Float16*)(qbb + (size_t)BB * 32 * 24576);
  _Float16* tp_h    = first_h + (size_t)BB * PP * DD;

  kQprep<<<dim3(QQ / 32, BB), 256, 0, stream>>>(ques, qbb);
  kA    <<<dim3(PP / 128, BB), 512, 0, stream>>>(pass, qbb, w_attn,
                                                 first_h, tp_h, rowmax, logit1);
  kB2   <<<dim3(32, BB), 256, 0, stream>>>(pass, rowmax, numpart, denpart);
  kB3   <<<BB, 256, 0, stream>>>(numpart, denpart, w_attn, tq, w2tq);
  kC    <<<dim3(32, BB), 256, 0, stream>>>(tp_h, logit1, w2tq, el);
  kE    <<<dim3(32, BB), 256, 0, stream>>>(tp_h, first_h, el, r1part, r2part, den2part);
  kF    <<<BB, 256, 0, stream>>>(r1part, r2part, den2part, tq, w_out, b_out, out);
}

// Round 3
// 362.115 us; speedup vs baseline: 1.0524x; 1.0463x over previous
//
#include <hip/hip_runtime.h>
#include <cmath>

#define BB 16
#define PP 4096
#define QQ 1024
#define DD 256

typedef __attribute__((ext_vector_type(8))) short short8;
typedef __attribute__((ext_vector_type(4))) float floatx4;
typedef __attribute__((ext_vector_type(4))) _Float16 half4;
typedef __attribute__((ext_vector_type(4))) unsigned short ushort4v;

static __device__ inline ushort bf16_rne(float x) {
  unsigned u = __float_as_uint(x);
  unsigned r = (u + 0x7fffu + ((u >> 16) & 1u)) >> 16;
  return (ushort)r;
}
static __device__ inline float bf16f(ushort h) { return __uint_as_float(((unsigned)h) << 16); }

static __device__ inline float ftanh(float x) {
  float e = __expf(2.0f * x);
  return 1.0f - 2.0f * __builtin_amdgcn_rcpf(e + 1.0f);
}

static __device__ inline void gl16(const void* g, void* l) {
  __builtin_amdgcn_global_load_lds(
      (const __attribute__((address_space(1))) unsigned int*)g,
      (__attribute__((address_space(3))) unsigned int*)l, 16, 0, 0);
}

// ---------------------------------------------------------------------------
// kQprep: Q -> per-(b,32q-tile) 48KB blobs: [SQhi 16K | SQlo 16K | TQhi 16K].
//  SQ: row-major hi/lo, granule j of row r at slot j^(r&7).
//  TQ: transposed [d][32q] bf16-hi only, granule k at slot k^((d>>1)&3).
// ---------------------------------------------------------------------------
__global__ __launch_bounds__(256) void kQprep(
    const float* __restrict__ ques, ushort* __restrict__ qb)
{
  const int b = blockIdx.y, qt = blockIdx.x;
  __shared__ float tile[32][260];
  const int tid = threadIdx.x;
  const float* src = ques + ((size_t)b * QQ + qt * 32) * DD;
  for (int i = tid; i < 32 * 64; i += 256) {
    int r = i >> 6, c = (i & 63) << 2;
    *(float4*)&tile[r][c] = *(const float4*)(src + r * DD + c);
  }
  __syncthreads();
  ushort* blob = qb + (size_t)(b * 32 + qt) * 24576;
  {
    int r = tid >> 3;
    int j0 = (tid & 7) * 4;
#pragma unroll
    for (int jj = 0; jj < 4; ++jj) {
      int j = j0 + jj;
      ushort h8[8], l8[8];
#pragma unroll
      for (int e = 0; e < 8; ++e) {
        float x = tile[r][j * 8 + e];
        ushort h = bf16_rne(x);
        h8[e] = h; l8[e] = bf16_rne(x - bf16f(h));
      }
      int g = r * 32 + (j ^ (r & 7));
      *(uint4*)&blob[(size_t)g * 8] = *(uint4*)h8;
      *(uint4*)&blob[8192 + (size_t)g * 8] = *(uint4*)l8;
    }
  }
  {
    int d = tid;
    int s = (d >> 1) & 3;
    ushort h32[32];
#pragma unroll
    for (int r = 0; r < 32; ++r) h32[r] = bf16_rne(tile[r][d]);
#pragma unroll
    for (int k = 0; k < 4; ++k)
      *(uint4*)&blob[16384 + (size_t)d * 32 + (k ^ s) * 8] = *(uint4*)&h32[k * 8];
  }
}

// ---------------------------------------------------------------------------
// kA: flash attention, K-split wave decomposition (fits 128 arch VGPR).
// 8 waves: (pp = w>>1) = 32-p block, (kh = w&1) = K-half of the d=256 dot.
// GEMM1: wave computes PARTIAL S^T (32q x 32p, K=128): A-reads 16/iter,
//        B-frags only 2pt x 4c x hi/lo = 64 VGPR.  Partners (same pp,
//        kh^1) exchange partials via 16KB Sbuf; wave kh softmaxes q-tile kh.
// GEMM2: wave = 4 p-tiles (kh*64..) x 4 d-tiles (pp*64..); P via LDS hi/lo.
// Per iter: DMA(t+1) | G1 | S-xchg [lgkm bar] | softmax+P-write [lgkm bar] |
//           G2 | syncthreads.  vmcnt only drained at the final barrier.
// ---------------------------------------------------------------------------
__global__ __launch_bounds__(512, 2) void kA(
    const float* __restrict__ pass, const ushort* __restrict__ qb,
    const float* __restrict__ w_attn,
    _Float16* __restrict__ first_h, _Float16* __restrict__ tp_h,
    float* __restrict__ rowmax, float* __restrict__ logit1)
{
  // buf0 @0 (48K) | buf1 @49152 (48K) | PbufH @98304 (8K) | PbufL @106496 (8K)
  // Sbuf @114688 (16K) | psb @133120 (1K) | mxb @134144 (1K)
  // epilogue Of @0 (128x260 f32 = 133120)
  __shared__ alignas(16) char sm[135168];

  const int b    = blockIdx.y;
  const int p0   = blockIdx.x * 128;
  const int tid  = threadIdx.x;
  const int w    = tid >> 6;
  const int lane = tid & 63;
  const int l15  = lane & 15;
  const int quad = lane >> 4;
  const int swz  = l15 & 7;

  const int pp = w >> 1;   // 32-p block (0..3); also GEMM2 d-quarter
  const int kh = w & 1;    // K-half (0/1); also softmax q-tile & GEMM2 p-half

  // passage B-fragments: 2 p-tiles x 4 K-chunks (this wave's K-half), hi/lo
  short8 bhi[2][4], blo[2][4];
#pragma unroll
  for (int pt = 0; pt < 2; ++pt) {
    const float* prow = pass + (((size_t)b * PP + p0 + pp * 32 + pt * 16 + l15) * DD);
#pragma unroll
    for (int c = 0; c < 4; ++c) {
      const float* p8 = prow + (kh * 4 + c) * 32 + quad * 8;
      float4 x0 = *(const float4*)p8;
      float4 x1 = *(const float4*)(p8 + 4);
      float xs[8] = {x0.x, x0.y, x0.z, x0.w, x1.x, x1.y, x1.z, x1.w};
#pragma unroll
      for (int j = 0; j < 8; ++j) {
        ushort h  = bf16_rne(xs[j]);
        ushort lo = bf16_rne(xs[j] - bf16f(h));
        bhi[pt][c][j] = (short)h;
        blo[pt][c][j] = (short)lo;
      }
    }
  }

  ushort* PbufH = (ushort*)(sm + 98304);
  ushort* PbufL = (ushort*)(sm + 106496);
  float*  Sbuf  = (float*)(sm + 114688);
  const int pgd   = kh * 2 + (quad >> 1);   // P-write q-granule
  const int psub  = (quad & 1) * 4;         // offset within granule
  const int vtoff = l15 * 32 + ((quad ^ ((l15 >> 1) & 3)) * 8);

  const ushort* tb = qb + (size_t)b * 32 * 24576;
  const int dma_l = w * 3072 + lane * 8;    // ushort offset in blob
  const int dma_s = w * 6144 + lane * 16;   // byte offset in LDS buffer

  floatx4 accO[4][4];   // [p-tile][d-tile]
#pragma unroll
  for (int i = 0; i < 4; ++i)
#pragma unroll
    for (int k = 0; k < 4; ++k) accO[i][k] = (floatx4){0.f, 0.f, 0.f, 0.f};
  float ps0 = 0.f, ps1 = 0.f, mx0 = -INFINITY, mx1 = -INFINITY;

  // DMA(0) -> buf0
  {
    const ushort* gs = tb + dma_l;
    char* ld = sm + dma_s;
#pragma unroll
    for (int i = 0; i < 6; ++i) gl16(gs + i * 512, ld + i * 1024);
  }
  __syncthreads();

  for (int t = 0; t < 32; ++t) {
    const char* cur = sm + (t & 1) * 49152;
    if (t < 31) {
      const ushort* gs = tb + (size_t)(t + 1) * 24576 + dma_l;
      char* ld = sm + ((t + 1) & 1) * 49152 + dma_s;
#pragma unroll
      for (int i = 0; i < 6; ++i) gl16(gs + i * 512, ld + i * 1024);
    }

    // ---- GEMM1(t): partial S^T (2qt x 2pt tiles), K = this wave's 128 ----
    const ushort* Qhi = (const ushort*)cur;
    const ushort* Qlo = (const ushort*)(cur + 16384);
    floatx4 s00 = (floatx4){0.f, 0.f, 0.f, 0.f};
    floatx4 s01 = (floatx4){0.f, 0.f, 0.f, 0.f};
    floatx4 s10 = (floatx4){0.f, 0.f, 0.f, 0.f};
    floatx4 s11 = (floatx4){0.f, 0.f, 0.f, 0.f};
    __builtin_amdgcn_s_setprio(1);
#pragma unroll
    for (int c = 0; c < 4; ++c) {
      const int go0 = l15 * 256 + (((kh * 16 + c * 4 + quad) ^ swz) << 3);
      short8 a0h = *(const short8*)&Qhi[go0];
      short8 a0l = *(const short8*)&Qlo[go0];
      short8 a1h = *(const short8*)&Qhi[go0 + 4096];
      short8 a1l = *(const short8*)&Qlo[go0 + 4096];
      s00 = __builtin_amdgcn_mfma_f32_16x16x32_bf16(a0h, bhi[0][c], s00, 0, 0, 0);
      s00 = __builtin_amdgcn_mfma_f32_16x16x32_bf16(a0h, blo[0][c], s00, 0, 0, 0);
      s00 = __builtin_amdgcn_mfma_f32_16x16x32_bf16(a0l, bhi[0][c], s00, 0, 0, 0);
      s01 = __builtin_amdgcn_mfma_f32_16x16x32_bf16(a0h, bhi[1][c], s01, 0, 0, 0);
      s01 = __builtin_amdgcn_mfma_f32_16x16x32_bf16(a0h, blo[1][c], s01, 0, 0, 0);
      s01 = __builtin_amdgcn_mfma_f32_16x16x32_bf16(a0l, bhi[1][c], s01, 0, 0, 0);
      s10 = __builtin_amdgcn_mfma_f32_16x16x32_bf16(a1h, bhi[0][c], s10, 0, 0, 0);
      s10 = __builtin_amdgcn_mfma_f32_16x16x32_bf16(a1h, blo[0][c], s10, 0, 0, 0);
      s10 = __builtin_amdgcn_mfma_f32_16x16x32_bf16(a1l, bhi[0][c], s10, 0, 0, 0);
      s11 = __builtin_amdgcn_mfma_f32_16x16x32_bf16(a1h, bhi[1][c], s11, 0, 0, 0);
      s11 = __builtin_amdgcn_mfma_f32_16x16x32_bf16(a1h, blo[1][c], s11, 0, 0, 0);
      s11 = __builtin_amdgcn_mfma_f32_16x16x32_bf16(a1l, bhi[1][c], s11, 0, 0, 0);
    }
    __builtin_amdgcn_s_setprio(0);

    // ---- S-exchange: write partials for qt=1-kh; read partner's qt=kh ----
    {
      float* dst = Sbuf + pp * 1024 + (1 - kh) * 512 + lane * 4;
      floatx4 w0 = kh ? s00 : s10;
      floatx4 w1 = kh ? s01 : s11;
      *(floatx4*)dst = w0;
      *(floatx4*)(dst + 256) = w1;
    }
    asm volatile("s_waitcnt lgkmcnt(0)" ::: "memory");
    __builtin_amdgcn_s_barrier();
    __builtin_amdgcn_sched_barrier(0);
    floatx4 sA, sB;
    {
      const float* src = Sbuf + pp * 1024 + kh * 512 + lane * 4;
      floatx4 o0 = *(const floatx4*)src;
      floatx4 o1 = *(const floatx4*)(src + 256);
      floatx4 own0 = kh ? s10 : s00;
      floatx4 own1 = kh ? s11 : s01;
      sA = own0 + o0;
      sB = own1 + o1;
    }

    // ---- softmax(t) on q-tile kh (fixed shift C=60) + P-write ----
    {
      ushort4v ph, pl;
#pragma unroll
      for (int r = 0; r < 4; ++r) {
        float v = sA[r];
        mx0 = fmaxf(mx0, v);
        float x = __expf(v - 60.f);
        ps0 += x;
        ushort h = bf16_rne(x);
        ph[r] = h; pl[r] = bf16_rne(x - bf16f(h));
      }
      const int wi = (((pp * 2 + 0) * 16 + l15) * 4 + (pgd ^ (l15 & 3))) * 8 + psub;
      *(ushort4v*)&PbufH[wi] = ph;
      *(ushort4v*)&PbufL[wi] = pl;
    }
    {
      ushort4v ph, pl;
#pragma unroll
      for (int r = 0; r < 4; ++r) {
        float v = sB[r];
        mx1 = fmaxf(mx1, v);
        float x = __expf(v - 60.f);
        ps1 += x;
        ushort h = bf16_rne(x);
        ph[r] = h; pl[r] = bf16_rne(x - bf16f(h));
      }
      const int wi = (((pp * 2 + 1) * 16 + l15) * 4 + (pgd ^ (l15 & 3))) * 8 + psub;
      *(ushort4v*)&PbufH[wi] = ph;
      *(ushort4v*)&PbufL[wi] = pl;
    }

    asm volatile("s_waitcnt lgkmcnt(0)" ::: "memory");
    __builtin_amdgcn_s_barrier();
    __builtin_amdgcn_sched_barrier(0);

    // ---- GEMM2(t): O(64p x 64d) += P * Vhi ----
    const ushort* TQ = (const ushort*)(cur + 32768);
    short8 vhi[4];
#pragma unroll
    for (int k = 0; k < 4; ++k)
      vhi[k] = *(const short8*)&TQ[(pp * 4 + k) * 512 + vtoff];
    __builtin_amdgcn_s_setprio(1);
#pragma unroll
    for (int pt = 0; pt < 4; ++pt) {
      const int ri = (((kh * 4 + pt) * 16 + l15) * 4 + (quad ^ (l15 & 3))) * 8;
      short8 phh = *(const short8*)&PbufH[ri];
      short8 pll = *(const short8*)&PbufL[ri];
#pragma unroll
      for (int k = 0; k < 4; ++k) {
        accO[pt][k] = __builtin_amdgcn_mfma_f32_16x16x32_bf16(phh, vhi[k], accO[pt][k], 0, 0, 0);
        accO[pt][k] = __builtin_amdgcn_mfma_f32_16x16x32_bf16(pll, vhi[k], accO[pt][k], 0, 0, 0);
      }
    }
    __builtin_amdgcn_s_setprio(0);
    __syncthreads();  // drain DMA(t+1); Pbuf/Sbuf reuse boundary
  }

  // ---- final reductions: quad-reduce, then cross-kh combine via LDS ----
  ps0 += __shfl_xor(ps0, 16); ps0 += __shfl_xor(ps0, 32);
  ps1 += __shfl_xor(ps1, 16); ps1 += __shfl_xor(ps1, 32);
  mx0 = fmaxf(mx0, __shfl_xor(mx0, 16)); mx0 = fmaxf(mx0, __shfl_xor(mx0, 32));
  mx1 = fmaxf(mx1, __shfl_xor(mx1, 16)); mx1 = fmaxf(mx1, __shfl_xor(mx1, 32));

  float* psb = (float*)(sm + 133120);  // [2 kh][128 p]
  float* mxb = (float*)(sm + 134144);
  if (lane < 16) {
    psb[kh * 128 + pp * 32 + l15]      = ps0;
    psb[kh * 128 + pp * 32 + 16 + l15] = ps1;
    mxb[kh * 128 + pp * 32 + l15]      = mx0;
    mxb[kh * 128 + pp * 32 + 16 + l15] = mx1;
  }
  __syncthreads();
  const float pstot = psb[w * 16 + l15] + psb[128 + w * 16 + l15];
  const float mxtot = fmaxf(mxb[w * 16 + l15], mxb[128 + w * 16 + l15]);
  const size_t rowoff = (size_t)b * PP + p0 + w * 16;
  if (lane < 16) rowmax[rowoff + lane] = mxtot;

  // ---- stage O to full-block scratch (rows x 260 f32) ----
  float* Of = (float*)sm;
#pragma unroll
  for (int pt = 0; pt < 4; ++pt)
#pragma unroll
    for (int k = 0; k < 4; ++k)
#pragma unroll
      for (int r = 0; r < 4; ++r)
        Of[(kh * 64 + pt * 16 + quad * 4 + r) * 260 + pp * 64 + k * 16 + l15] =
            accO[pt][k][r];
  __syncthreads();

  // ---- row pass: normalize, tanh-fuse, store halves, logit1 dot ----
  const float4 w1 = *(const float4*)(w_attn + lane * 4);
#pragma unroll
  for (int j = 0; j < 16; ++j) {
    float4 o = *(const float4*)&Of[(w * 16 + j) * 260 + lane * 4];
    float linv = 1.f / __shfl(pstot, j);
    float4 pv4 = *(const float4*)(pass + (rowoff + j) * DD + lane * 4);
    float tpx = ftanh(pv4.x), tpy = ftanh(pv4.y), tpz = ftanh(pv4.z), tpw = ftanh(pv4.w);
    float4 f;
    f.x = tpx * ftanh(o.x * linv);
    f.y = tpy * ftanh(o.y * linv);
    f.z = tpz * ftanh(o.z * linv);
    f.w = tpw * ftanh(o.w * linv);
    half4 fh = {(_Float16)f.x, (_Float16)f.y, (_Float16)f.z, (_Float16)f.w};
    half4 th = {(_Float16)tpx, (_Float16)tpy, (_Float16)tpz, (_Float16)tpw};
    *(half4*)(first_h + (rowoff + j) * DD + lane * 4) = fh;
    *(half4*)(tp_h + (rowoff + j) * DD + lane * 4) = th;
    float part = f.x * w1.x + f.y * w1.y + f.z * w1.z + f.w * w1.w;
    part += __shfl_xor(part, 1);  part += __shfl_xor(part, 2);
    part += __shfl_xor(part, 4);  part += __shfl_xor(part, 8);
    part += __shfl_xor(part, 16); part += __shfl_xor(part, 32);
    if (lane == 0) logit1[rowoff + j] = part;
  }
}

// ---------------------------------------------------------------------------
// kB2: q2c partials with unnormalized weights e^{rowmax-60}. No atomics.
// ---------------------------------------------------------------------------
__global__ __launch_bounds__(256) void kB2(
    const float* __restrict__ pass, const float* __restrict__ rowmax,
    float* __restrict__ numpart, float* __restrict__ denpart)
{
  const int b = blockIdx.y, chunk = blockIdx.x;   // 32 chunks x 128 p
  const int tid = threadIdx.x, r = tid >> 6, ln = tid & 63;
  __shared__ float sacc[4][64][4];
  __shared__ float sden[4][64];
  const float* rm = rowmax + (size_t)b * PP + chunk * 128;
  const float* pb = pass + ((size_t)b * PP + chunk * 128) * DD;
  float4 acc = make_float4(0.f, 0.f, 0.f, 0.f);
  float den = 0.f;
  for (int p = r; p < 128; p += 4) {
    float wgt = __expf(rm[p] - 60.f);
    float4 v = *(const float4*)(pb + (size_t)p * DD + ln * 4);
    acc.x += wgt * v.x; acc.y += wgt * v.y;
    acc.z += wgt * v.z; acc.w += wgt * v.w;
    den += wgt;
  }
  *(float4*)&sacc[r][ln][0] = acc;
  sden[r][ln] = den;
  __syncthreads();
  if (r == 0) {
    float4 s;
    s.x = sacc[0][ln][0] + sacc[1][ln][0] + sacc[2][ln][0] + sacc[3][ln][0];
    s.y = sacc[0][ln][1] + sacc[1][ln][1] + sacc[2][ln][1] + sacc[3][ln][1];
    s.z = sacc[0][ln][2] + sacc[1][ln][2] + sacc[2][ln][2] + sacc[3][ln][2];
    s.w = sacc[0][ln][3] + sacc[1][ln][3] + sacc[2][ln][3] + sacc[3][ln][3];
    *(float4*)(numpart + (size_t)(chunk * 16 + b) * DD + ln * 4) = s;
    if (ln == 0)
      denpart[chunk * 16 + b] = sden[0][0] + sden[1][0] + sden[2][0] + sden[3][0];
  }
}

// kB3: reduce partials -> q2c -> tq, w2tq
__global__ void kB3(const float* __restrict__ numpart, const float* __restrict__ denpart,
                    const float* __restrict__ w_attn,
                    float* __restrict__ tq, float* __restrict__ w2tq)
{
  const int b = blockIdx.x, d = threadIdx.x;
  float den = 0.f, num = 0.f;
#pragma unroll
  for (int c = 0; c < 32; ++c) {
    den += denpart[c * 16 + b];
    num += numpart[(size_t)(c * 16 + b) * DD + d];
  }
  float t = ftanh(num / den);
  tq[b * DD + d] = t;
  w2tq[b * DD + d] = w_attn[DD + d] * t;
}

// kC: el[p] = exp(logit1 + dot(tp, w2tq))   (unnormalized logit weight)
__global__ __launch_bounds__(256) void kC(
    const _Float16* __restrict__ tp_h, const float* __restrict__ logit1,
    const float* __restrict__ w2tq, float* __restrict__ el)
{
  const int b = blockIdx.y, chunk = blockIdx.x;  // 32 chunks x 128 p
  const int wave = threadIdx.x >> 6, lane = threadIdx.x & 63;
  const float4 wv = *(const float4*)(w2tq + b * DD + (lane << 2));
  const int pbase = chunk * 128 + wave * 32;
  for (int j = 0; j < 32; ++j) {
    int p = pbase + j;
    half4 tv = *(const half4*)(tp_h + ((size_t)b * PP + p) * DD + (lane << 2));
    float part = (float)tv.x * wv.x + (float)tv.y * wv.y +
                 (float)tv.z * wv.z + (float)tv.w * wv.w;
    part += __shfl_xor(part, 1);  part += __shfl_xor(part, 2);
    part += __shfl_xor(part, 4);  part += __shfl_xor(part, 8);
    part += __shfl_xor(part, 16); part += __shfl_xor(part, 32);
    if (lane == 0)
      el[(size_t)b * PP + p] = __expf(logit1[(size_t)b * PP + p] + part);
  }
}

// kE: reducer partials (no atomics, half4 vector loads)
__global__ __launch_bounds__(256) void kE(
    const _Float16* __restrict__ tp_h, const _Float16* __restrict__ first_h,
    const float* __restrict__ el,
    float* __restrict__ r1part, float* __restrict__ r2part, float* __restrict__ den2part)
{
  const int b = blockIdx.y, chunk = blockIdx.x;   // 32 chunks x 128 p
  const int tid = threadIdx.x, r = tid >> 6, ln = tid & 63;
  __shared__ float s1[4][64][4];
  __shared__ float s2[4][64][4];
  __shared__ float sd[4][64];
  const float* ev = el + (size_t)b * PP + chunk * 128;
  const size_t base = ((size_t)b * PP + chunk * 128) * DD;
  float a1[4] = {0.f, 0.f, 0.f, 0.f}, a2[4] = {0.f, 0.f, 0.f, 0.f};
  float den = 0.f;
  for (int p = r; p < 128; p += 4) {
    float wgt = ev[p];
    half4 f = *(const half4*)(first_h + base + (size_t)p * DD + ln * 4);
    half4 t = *(const half4*)(tp_h + base + (size_t)p * DD + ln * 4);
    a1[0] += wgt * (float)f.x; a1[1] += wgt * (float)f.y;
    a1[2] += wgt * (float)f.z; a1[3] += wgt * (float)f.w;
    a2[0] += wgt * (float)t.x; a2[1] += wgt * (float)t.y;
    a2[2] += wgt * (float)t.z; a2[3] += wgt * (float)t.w;
    den += wgt;
  }
  *(float4*)&s1[r][ln][0] = *(float4*)a1;
  *(float4*)&s2[r][ln][0] = *(float4*)a2;
  sd[r][ln] = den;
  __syncthreads();
  if (r == 0) {
    float o1[4], o2[4];
#pragma unroll
    for (int i = 0; i < 4; ++i) {
      o1[i] = s1[0][ln][i] + s1[1][ln][i] + s1[2][ln][i] + s1[3][ln][i];
      o2[i] = s2[0][ln][i] + s2[1][ln][i] + s2[2][ln][i] + s2[3][ln][i];
    }
    *(float4*)(r1part + (size_t)(chunk * 16 + b) * DD + ln * 4) = *(float4*)o1;
    *(float4*)(r2part + (size_t)(chunk * 16 + b) * DD + ln * 4) = *(float4*)o2;
    if (ln == 0)
      den2part[chunk * 16 + b] = sd[0][0] + sd[1][0] + sd[2][0] + sd[3][0];
  }
}

// kF: reduce partials, normalize, output GEMM
__global__ __launch_bounds__(256) void kF(
    const float* __restrict__ r1part, const float* __restrict__ r2part,
    const float* __restrict__ den2part, const float* __restrict__ tq,
    const float* __restrict__ w_out, const float* __restrict__ b_out,
    float* __restrict__ out)
{
  const int b = blockIdx.x, o = threadIdx.x;
  __shared__ float R1[256], R2[256];
  float den = 0.f, red1 = 0.f, red2 = 0.f;
#pragma unroll
  for (int c = 0; c < 32; ++c) {
    den += den2part[c * 16 + b];
    red1 += r1part[(size_t)(c * 16 + b) * DD + o];
    red2 += r2part[(size_t)(c * 16 + b) * DD + o];
  }
  float inv = 1.f / den;
  R1[o] = red1 * inv;
  R2[o] = red2 * inv * tq[b * DD + o];
  __syncthreads();
  float acc = b_out[o];
  for (int k = 0; k < DD; ++k)
    acc += R1[k] * w_out[k * 256 + o];
  for (int k = 0; k < DD; ++k)
    acc += R2[k] * w_out[(DD + k) * 256 + o];
  out[b * 256 + o] = acc;
}

extern "C" void kernel_launch(void* const* d_in, const int* in_sizes, int n_in,
                              void* d_out, int out_size, void* d_ws, size_t ws_size,
                              hipStream_t stream) {
  const float* pass   = (const float*)d_in[0];
  const float* ques   = (const float*)d_in[1];
  const float* w_attn = (const float*)d_in[2];
  // d_in[3] = b_attn: uniform softmax shift, cancels in num/den -> dropped
  const float* w_out  = (const float*)d_in[4];
  const float* b_out  = (const float*)d_in[5];
  float* out = (float*)d_out;

  float* ws       = (float*)d_ws;
  float* rowmax   = ws;                                   // BB*PP
  float* logit1   = rowmax   + (size_t)BB * PP;           // BB*PP
  float* el       = logit1   + (size_t)BB * PP;           // BB*PP
  float* numpart  = el       + (size_t)BB * PP;           // 32*BB*DD
  float* denpart  = numpart  + (size_t)32 * BB * DD;      // 32*BB
  float* r1part   = denpart  + 32 * BB;                   // 32*BB*DD
  float* r2part   = r1part   + (size_t)32 * BB * DD;      // 32*BB*DD
  float* den2part = r2part   + (size_t)32 * BB * DD;      // 32*BB
  float* tq       = den2part + 32 * BB;                   // BB*DD
  float* w2tq     = tq       + BB * DD;                   // BB*DD
  ushort* qbb     = (ushort*)(w2tq + BB * DD);            // BB*32*24576 ushorts
  _Float16* first_h = (_Float16*)(qbb + (size_t)BB * 32 * 24576);
  _Float16* tp_h    = first_h + (size_t)BB * PP * DD;

  kQprep<<<dim3(QQ / 32, BB), 256, 0, stream>>>(ques, qbb);
  kA    <<<dim3(PP / 128, BB), 512, 0, stream>>>(pass, qbb, w_attn,
                                                 first_h, tp_h, rowmax, logit1);
  kB2   <<<dim3(32, BB), 256, 0, stream>>>(pass, rowmax, numpart, denpart);
  kB3   <<<BB, 256, 0, stream>>>(numpart, denpart, w_attn, tq, w2tq);
  kC    <<<dim3(32, BB), 256, 0, stream>>>(tp_h, logit1, w2tq, el);
  kE    <<<dim3(32, BB), 256, 0, stream>>>(tp_h, first_h, el, r1part, r2part, den2part);
  kF    <<<BB, 256, 0, stream>>>(r1part, r2part, den2part, tq, w_out, b_out, out);
}

// Round 4
// 328.261 us; speedup vs baseline: 1.1609x; 1.1031x over previous
//
#include <hip/hip_runtime.h>
#include <cmath>

#define BB 16
#define PP 4096
#define QQ 1024
#define DD 256

typedef __attribute__((ext_vector_type(8))) short short8;
typedef __attribute__((ext_vector_type(4))) float floatx4;
typedef __attribute__((ext_vector_type(4))) _Float16 half4;

static __device__ inline ushort bf16_rne(float x) {
  unsigned u = __float_as_uint(x);
  unsigned r = (u + 0x7fffu + ((u >> 16) & 1u)) >> 16;
  return (ushort)r;
}
static __device__ inline float bf16f(ushort h) { return __uint_as_float(((unsigned)h) << 16); }

static __device__ inline float ftanh(float x) {
  float e = __expf(2.0f * x);
  return 1.0f - 2.0f * __builtin_amdgcn_rcpf(e + 1.0f);
}

static __device__ inline void gl16(const void* g, void* l) {
  __builtin_amdgcn_global_load_lds(
      (const __attribute__((address_space(1))) unsigned int*)g,
      (__attribute__((address_space(3))) unsigned int*)l, 16, 0, 0);
}

// ---------------------------------------------------------------------------
// kQprep: Q -> per-(b,32q-tile) 48KB blobs: [SQhi 16K | SQlo 16K | TQhi 16K].
//  SQ: row-major hi/lo, granule j of row r at slot j^(r&7).
//  TQ: transposed [d][32q] bf16-hi only, granule k at slot k^((d>>1)&3).
// ---------------------------------------------------------------------------
__global__ __launch_bounds__(256) void kQprep(
    const float* __restrict__ ques, ushort* __restrict__ qb)
{
  const int b = blockIdx.y, qt = blockIdx.x;
  __shared__ float tile[32][260];
  const int tid = threadIdx.x;
  const float* src = ques + ((size_t)b * QQ + qt * 32) * DD;
  for (int i = tid; i < 32 * 64; i += 256) {
    int r = i >> 6, c = (i & 63) << 2;
    *(float4*)&tile[r][c] = *(const float4*)(src + r * DD + c);
  }
  __syncthreads();
  ushort* blob = qb + (size_t)(b * 32 + qt) * 24576;
  {
    int r = tid >> 3;
    int j0 = (tid & 7) * 4;
#pragma unroll
    for (int jj = 0; jj < 4; ++jj) {
      int j = j0 + jj;
      ushort h8[8], l8[8];
#pragma unroll
      for (int e = 0; e < 8; ++e) {
        float x = tile[r][j * 8 + e];
        ushort h = bf16_rne(x);
        h8[e] = h; l8[e] = bf16_rne(x - bf16f(h));
      }
      int g = r * 32 + (j ^ (r & 7));
      *(uint4*)&blob[(size_t)g * 8] = *(uint4*)h8;
      *(uint4*)&blob[8192 + (size_t)g * 8] = *(uint4*)l8;
    }
  }
  {
    int d = tid;
    int s = (d >> 1) & 3;
    ushort h32[32];
#pragma unroll
    for (int r = 0; r < 32; ++r) h32[r] = bf16_rne(tile[r][d]);
#pragma unroll
    for (int k = 0; k < 4; ++k)
      *(uint4*)&blob[16384 + (size_t)d * 32 + (k ^ s) * 8] = *(uint4*)&h32[k * 8];
  }
}

// ---------------------------------------------------------------------------
// kA: flash attention, cross-iteration pipelined (round-0 structure).
// 512 thr = 8 waves x 16 p-rows; triple-buffered 48KB Q tiles (1 block/CU).
// iter t: DMA(t+1) | GEMM1(t) | GEMM2(t-1) (P in regs) | softmax(t) | Ptrans(t).
// Fixed-shift softmax (C=60), l/rowmax reductions deferred to the end.
// Epilogue additionally FUSES kB2: per-block q2c partials
//   numpart[chunk][b][d] = sum_p exp(mx_p-60) * pass[p][d], denpart likewise.
// ---------------------------------------------------------------------------
__global__ __launch_bounds__(512, 1) void kA(
    const float* __restrict__ pass, const ushort* __restrict__ qb,
    const float* __restrict__ w_attn,
    _Float16* __restrict__ first_h, _Float16* __restrict__ tp_h,
    float* __restrict__ logit1,
    float* __restrict__ numpart, float* __restrict__ denpart)
{
  __shared__ alignas(16) char sm[147456];  // 3 x 48KB buffers

  const int b    = blockIdx.y;
  const int p0   = blockIdx.x * 128;
  const int tid  = threadIdx.x;
  const int w    = tid >> 6;
  const int lane = tid & 63;
  const int l15  = lane & 15;
  const int quad = lane >> 4;
  const int swz  = l15 & 7;

  // passage B-fragments (hi/lo), once per block
  short8 bhi[8], blo[8];
  {
    const float* prow = pass + (((size_t)b * PP + p0 + w * 16 + l15) * DD);
#pragma unroll
    for (int c = 0; c < 8; ++c) {
      const float* p8 = prow + c * 32 + quad * 8;
      float4 x0 = *(const float4*)p8;
      float4 x1 = *(const float4*)(p8 + 4);
      float xs[8] = {x0.x, x0.y, x0.z, x0.w, x1.x, x1.y, x1.z, x1.w};
#pragma unroll
      for (int j = 0; j < 8; ++j) {
        ushort h = bf16_rne(xs[j]);
        ushort lo = bf16_rne(xs[j] - bf16f(h));
        bhi[c][j] = (short)h;
        blo[c][j] = (short)lo;
      }
    }
  }

  int goff[8];
#pragma unroll
  for (int c = 0; c < 8; ++c) goff[c] = (l15 * 32 + ((4 * c + quad) ^ swz)) * 8;
  const int vtoff = l15 * 32 + ((quad ^ ((l15 >> 1) & 3)) * 8);

  const ushort* tb = qb + (size_t)b * 32 * 24576;
  const int dma_l = w * 3072 + lane * 8;   // ushort offset in blob
  const int dma_s = w * 6144 + lane * 16;  // byte offset in LDS buffer

  floatx4 accO[16];
#pragma unroll
  for (int i = 0; i < 16; ++i) accO[i] = (floatx4){0.f, 0.f, 0.f, 0.f};
  float mx = -INFINITY, ps = 0.f;
  short8 phi = {0, 0, 0, 0, 0, 0, 0, 0}, plo = {0, 0, 0, 0, 0, 0, 0, 0};

  // DMA(0) -> buf0
  {
    const ushort* gs = tb + dma_l;
    char* ld = sm + dma_s;
#pragma unroll
    for (int i = 0; i < 6; ++i) gl16(gs + i * 512, ld + i * 1024);
  }
  __syncthreads();

  for (int t = 0; t < 32; ++t) {
    const int ic = t % 3, ip = (t + 2) % 3, inx = (t + 1) % 3;
    char* cur = sm + ic * 49152;
    char* prv = sm + ip * 49152;
    if (t < 31) {
      const ushort* gs = tb + (size_t)(t + 1) * 24576 + dma_l;
      char* ld = sm + inx * 49152 + dma_s;
#pragma unroll
      for (int i = 0; i < 6; ++i) gl16(gs + i * 512, ld + i * 1024);
    }

    // ---- GEMM1(t): S^T(32q x 16p), 3-term split ----
    const ushort* Qhi = (const ushort*)cur;
    const ushort* Qlo = (const ushort*)(cur + 16384);
    floatx4 s0 = (floatx4){0.f, 0.f, 0.f, 0.f};
    floatx4 s1 = (floatx4){0.f, 0.f, 0.f, 0.f};
#pragma unroll
    for (int c = 0; c < 8; ++c) {
      short8 a0h = *(const short8*)&Qhi[goff[c]];
      short8 a0l = *(const short8*)&Qlo[goff[c]];
      short8 a1h = *(const short8*)&Qhi[goff[c] + 4096];
      short8 a1l = *(const short8*)&Qlo[goff[c] + 4096];
      s0 = __builtin_amdgcn_mfma_f32_16x16x32_bf16(a0h, bhi[c], s0, 0, 0, 0);
      s0 = __builtin_amdgcn_mfma_f32_16x16x32_bf16(a0h, blo[c], s0, 0, 0, 0);
      s0 = __builtin_amdgcn_mfma_f32_16x16x32_bf16(a0l, bhi[c], s0, 0, 0, 0);
      s1 = __builtin_amdgcn_mfma_f32_16x16x32_bf16(a1h, bhi[c], s1, 0, 0, 0);
      s1 = __builtin_amdgcn_mfma_f32_16x16x32_bf16(a1h, blo[c], s1, 0, 0, 0);
      s1 = __builtin_amdgcn_mfma_f32_16x16x32_bf16(a1l, bhi[c], s1, 0, 0, 0);
    }

    // ---- GEMM2(t-1): O += P(t-1)*Vhi(t-1), 2-term (phi,plo in regs) ----
    if (t > 0) {
      const ushort* TQ = (const ushort*)(prv + 32768);
#pragma unroll
      for (int nt = 0; nt < 16; ++nt) {
        short8 vhi = *(const short8*)&TQ[nt * 512 + vtoff];
        accO[nt] = __builtin_amdgcn_mfma_f32_16x16x32_bf16(phi, vhi, accO[nt], 0, 0, 0);
        accO[nt] = __builtin_amdgcn_mfma_f32_16x16x32_bf16(plo, vhi, accO[nt], 0, 0, 0);
      }
    }

    // ---- softmax(t): fixed shift, deferred reductions ----
    float pv[8];
#pragma unroll
    for (int r = 0; r < 4; ++r) {
      float s = s0[r];
      mx = fmaxf(mx, s);
      pv[r] = __expf(s - 60.f);
      ps += pv[r];
    }
#pragma unroll
    for (int r = 0; r < 4; ++r) {
      float s = s1[r];
      mx = fmaxf(mx, s);
      pv[4 + r] = __expf(s - 60.f);
      ps += pv[4 + r];
    }

    // ---- Ptrans(t): via dead SQhi of prv (same-wave, private slice) ----
    // hi = truncated bf16 (AND), lo = rne of the exact residual.
    unsigned* pwv = (unsigned*)prv + w * 512;
#pragma unroll
    for (int mt = 0; mt < 2; ++mt) {
      unsigned pk[4];
#pragma unroll
      for (int r = 0; r < 4; ++r) {
        float x = pv[mt * 4 + r];
        unsigned u = __float_as_uint(x);
        unsigned hb = u & 0xffff0000u;
        ushort lo = bf16_rne(x - __uint_as_float(hb));
        pk[r] = (hb >> 16) | ((unsigned)lo << 16);
      }
      int g = l15 * 8 + ((mt * 4 + quad) ^ swz);
      *(uint4*)&pwv[g * 4] = *(uint4*)pk;
    }
    uint4 u0 = *(const uint4*)&pwv[(l15 * 8 + ((2 * quad) ^ swz)) * 4];
    uint4 u1 = *(const uint4*)&pwv[(l15 * 8 + ((2 * quad + 1) ^ swz)) * 4];
    unsigned ua[8] = {u0.x, u0.y, u0.z, u0.w, u1.x, u1.y, u1.z, u1.w};
#pragma unroll
    for (int j = 0; j < 8; ++j) {
      phi[j] = (short)(ua[j] & 0xffffu);
      plo[j] = (short)(ua[j] >> 16);
    }
    __syncthreads();  // drain own DMA(t+1); phase boundary
  }

  // ---- GEMM2(31): tile 31 lives in buf[31%3 = 1] ----
  {
    const ushort* TQ = (const ushort*)(sm + 49152 + 32768);
#pragma unroll
    for (int nt = 0; nt < 16; ++nt) {
      short8 vhi = *(const short8*)&TQ[nt * 512 + vtoff];
      accO[nt] = __builtin_amdgcn_mfma_f32_16x16x32_bf16(phi, vhi, accO[nt], 0, 0, 0);
      accO[nt] = __builtin_amdgcn_mfma_f32_16x16x32_bf16(plo, vhi, accO[nt], 0, 0, 0);
    }
  }

  // ---- final reductions (once) ----
  ps += __shfl_xor(ps, 16);
  ps += __shfl_xor(ps, 32);
  mx = fmaxf(mx, __shfl_xor(mx, 16));
  mx = fmaxf(mx, __shfl_xor(mx, 32));

  // ---- epilogue ----
  __syncthreads();  // all waves done with buffers before Of scratch reuse
  float* Of = (float*)(sm + w * 16640);  // 16 x 260 fp32 per wave
#pragma unroll
  for (int nt = 0; nt < 16; ++nt)
#pragma unroll
    for (int r = 0; r < 4; ++r)
      Of[(quad * 4 + r) * 260 + nt * 16 + l15] = accO[nt][r];
  const float4 w1 = *(const float4*)(w_attn + lane * 4);
  const size_t rowoff = (size_t)b * PP + p0 + w * 16;
  float4 qacc = make_float4(0.f, 0.f, 0.f, 0.f);
  float dacc = 0.f;
#pragma unroll
  for (int j = 0; j < 16; ++j) {
    float4 o = *(const float4*)&Of[j * 260 + lane * 4];
    float linv = 1.f / __shfl(ps, j);
    float4 pv4 = *(const float4*)(pass + (rowoff + j) * DD + lane * 4);
    // fused kB2: q2c partial with weight e^{rowmax-60}
    float wj = __expf(__shfl(mx, j) - 60.f);
    qacc.x += wj * pv4.x; qacc.y += wj * pv4.y;
    qacc.z += wj * pv4.z; qacc.w += wj * pv4.w;
    dacc += wj;
    float tpx = ftanh(pv4.x), tpy = ftanh(pv4.y), tpz = ftanh(pv4.z), tpw = ftanh(pv4.w);
    float4 f;
    f.x = tpx * ftanh(o.x * linv);
    f.y = tpy * ftanh(o.y * linv);
    f.z = tpz * ftanh(o.z * linv);
    f.w = tpw * ftanh(o.w * linv);
    half4 fh = {(_Float16)f.x, (_Float16)f.y, (_Float16)f.z, (_Float16)f.w};
    half4 th = {(_Float16)tpx, (_Float16)tpy, (_Float16)tpz, (_Float16)tpw};
    *(half4*)(first_h + (rowoff + j) * DD + lane * 4) = fh;
    *(half4*)(tp_h + (rowoff + j) * DD + lane * 4) = th;
    float part = f.x * w1.x + f.y * w1.y + f.z * w1.z + f.w * w1.w;
    part += __shfl_xor(part, 1);  part += __shfl_xor(part, 2);
    part += __shfl_xor(part, 4);  part += __shfl_xor(part, 8);
    part += __shfl_xor(part, 16); part += __shfl_xor(part, 32);
    if (lane == 0) logit1[rowoff + j] = part;
  }

  // ---- fused kB2 reduction: 8 per-wave partials -> numpart/denpart ----
  float* redw = (float*)(sm + w * 16640);  // own Of slice, reads all done
  *(float4*)&redw[lane * 4] = qacc;
  if (lane == 0) redw[256] = dacc;
  __syncthreads();
  if (w == 0) {
    float4 s = make_float4(0.f, 0.f, 0.f, 0.f);
    float dsum = 0.f;
#pragma unroll
    for (int wv = 0; wv < 8; ++wv) {
      const float* rp = (const float*)(sm + wv * 16640);
      float4 v = *(const float4*)&rp[lane * 4];
      s.x += v.x; s.y += v.y; s.z += v.z; s.w += v.w;
      dsum += rp[256];
    }
    *(float4*)(numpart + (size_t)(blockIdx.x * 16 + b) * DD + lane * 4) = s;
    if (lane == 0) denpart[blockIdx.x * 16 + b] = dsum;
  }
}

// kB3: reduce partials -> q2c -> tq, w2tq
__global__ void kB3(const float* __restrict__ numpart, const float* __restrict__ denpart,
                    const float* __restrict__ w_attn,
                    float* __restrict__ tq, float* __restrict__ w2tq)
{
  const int b = blockIdx.x, d = threadIdx.x;
  float den = 0.f, num = 0.f;
#pragma unroll
  for (int c = 0; c < 32; ++c) {
    den += denpart[c * 16 + b];
    num += numpart[(size_t)(c * 16 + b) * DD + d];
  }
  float t = ftanh(num / den);
  tq[b * DD + d] = t;
  w2tq[b * DD + d] = w_attn[DD + d] * t;
}

// kE: fused kC + reducer partials.  Per row p: logit-dot from tp_h (exactly
// kC's op order), wgt = exp(logit1 + dot); accumulate weighted f/t partials.
__global__ __launch_bounds__(256) void kE(
    const _Float16* __restrict__ tp_h, const _Float16* __restrict__ first_h,
    const float* __restrict__ logit1, const float* __restrict__ w2tq,
    float* __restrict__ r1part, float* __restrict__ r2part, float* __restrict__ den2part)
{
  const int b = blockIdx.y, chunk = blockIdx.x;   // 32 chunks x 128 p
  const int tid = threadIdx.x, r = tid >> 6, ln = tid & 63;
  __shared__ float s1[4][64][4];
  __shared__ float s2[4][64][4];
  __shared__ float sd[4][64];
  const float4 wv = *(const float4*)(w2tq + b * DD + (ln << 2));
  const float* lg = logit1 + (size_t)b * PP + chunk * 128;
  const size_t base = ((size_t)b * PP + chunk * 128) * DD;
  float a1[4] = {0.f, 0.f, 0.f, 0.f}, a2[4] = {0.f, 0.f, 0.f, 0.f};
  float den = 0.f;
  for (int p = r; p < 128; p += 4) {
    half4 f = *(const half4*)(first_h + base + (size_t)p * DD + ln * 4);
    half4 t = *(const half4*)(tp_h + base + (size_t)p * DD + ln * 4);
    float part = (float)t.x * wv.x + (float)t.y * wv.y +
                 (float)t.z * wv.z + (float)t.w * wv.w;
    part += __shfl_xor(part, 1);  part += __shfl_xor(part, 2);
    part += __shfl_xor(part, 4);  part += __shfl_xor(part, 8);
    part += __shfl_xor(part, 16); part += __shfl_xor(part, 32);
    float wgt = __expf(lg[p] + part);
    a1[0] += wgt * (float)f.x; a1[1] += wgt * (float)f.y;
    a1[2] += wgt * (float)f.z; a1[3] += wgt * (float)f.w;
    a2[0] += wgt * (float)t.x; a2[1] += wgt * (float)t.y;
    a2[2] += wgt * (float)t.z; a2[3] += wgt * (float)t.w;
    den += wgt;
  }
  *(float4*)&s1[r][ln][0] = *(float4*)a1;
  *(float4*)&s2[r][ln][0] = *(float4*)a2;
  sd[r][ln] = den;
  __syncthreads();
  if (r == 0) {
    float o1[4], o2[4];
#pragma unroll
    for (int i = 0; i < 4; ++i) {
      o1[i] = s1[0][ln][i] + s1[1][ln][i] + s1[2][ln][i] + s1[3][ln][i];
      o2[i] = s2[0][ln][i] + s2[1][ln][i] + s2[2][ln][i] + s2[3][ln][i];
    }
    *(float4*)(r1part + (size_t)(chunk * 16 + b) * DD + ln * 4) = *(float4*)o1;
    *(float4*)(r2part + (size_t)(chunk * 16 + b) * DD + ln * 4) = *(float4*)o2;
    if (ln == 0)
      den2part[chunk * 16 + b] = sd[0][0] + sd[1][0] + sd[2][0] + sd[3][0];
  }
}

// kF: reduce partials, normalize, output GEMM
__global__ __launch_bounds__(256) void kF(
    const float* __restrict__ r1part, const float* __restrict__ r2part,
    const float* __restrict__ den2part, const float* __restrict__ tq,
    const float* __restrict__ w_out, const float* __restrict__ b_out,
    float* __restrict__ out)
{
  const int b = blockIdx.x, o = threadIdx.x;
  __shared__ float R1[256], R2[256];
  float den = 0.f, red1 = 0.f, red2 = 0.f;
#pragma unroll
  for (int c = 0; c < 32; ++c) {
    den += den2part[c * 16 + b];
    red1 += r1part[(size_t)(c * 16 + b) * DD + o];
    red2 += r2part[(size_t)(c * 16 + b) * DD + o];
  }
  float inv = 1.f / den;
  R1[o] = red1 * inv;
  R2[o] = red2 * inv * tq[b * DD + o];
  __syncthreads();
  float acc = b_out[o];
  for (int k = 0; k < DD; ++k)
    acc += R1[k] * w_out[k * 256 + o];
  for (int k = 0; k < DD; ++k)
    acc += R2[k] * w_out[(DD + k) * 256 + o];
  out[b * 256 + o] = acc;
}

extern "C" void kernel_launch(void* const* d_in, const int* in_sizes, int n_in,
                              void* d_out, int out_size, void* d_ws, size_t ws_size,
                              hipStream_t stream) {
  const float* pass   = (const float*)d_in[0];
  const float* ques   = (const float*)d_in[1];
  const float* w_attn = (const float*)d_in[2];
  // d_in[3] = b_attn: uniform softmax shift, cancels in num/den -> dropped
  const float* w_out  = (const float*)d_in[4];
  const float* b_out  = (const float*)d_in[5];
  float* out = (float*)d_out;

  float* ws       = (float*)d_ws;
  float* rowmax   = ws;                                   // BB*PP (unused)
  float* logit1   = rowmax   + (size_t)BB * PP;           // BB*PP
  float* el       = logit1   + (size_t)BB * PP;           // BB*PP (unused)
  float* numpart  = el       + (size_t)BB * PP;           // 32*BB*DD
  float* denpart  = numpart  + (size_t)32 * BB * DD;      // 32*BB
  float* r1part   = denpart  + 32 * BB;                   // 32*BB*DD
  float* r2part   = r1part   + (size_t)32 * BB * DD;      // 32*BB*DD
  float* den2part = r2part   + (size_t)32 * BB * DD;      // 32*BB
  float* tq       = den2part + 32 * BB;                   // BB*DD
  float* w2tq     = tq       + BB * DD;                   // BB*DD
  ushort* qbb     = (ushort*)(w2tq + BB * DD);            // BB*32*24576 ushorts
  _Float16* first_h = (_Float16*)(qbb + (size_t)BB * 32 * 24576);
  _Float16* tp_h    = first_h + (size_t)BB * PP * DD;

  kQprep<<<dim3(QQ / 32, BB), 256, 0, stream>>>(ques, qbb);
  kA    <<<dim3(PP / 128, BB), 512, 0, stream>>>(pass, qbb, w_attn,
                                                 first_h, tp_h, logit1,
                                                 numpart, denpart);
  kB3   <<<BB, 256, 0, stream>>>(numpart, denpart, w_attn, tq, w2tq);
  kE    <<<dim3(32, BB), 256, 0, stream>>>(tp_h, first_h, logit1, w2tq,
                                           r1part, r2part, den2part);
  kF    <<<BB, 256, 0, stream>>>(r1part, r2part, den2part, tq, w_out, b_out, out);
}

// Round 5
// 327.396 us; speedup vs baseline: 1.1640x; 1.0026x over previous
//
#include <hip/hip_runtime.h>
#include <cmath>

#define BB 16
#define PP 4096
#define QQ 1024
#define DD 256

typedef __attribute__((ext_vector_type(8))) short short8;
typedef __attribute__((ext_vector_type(4))) float floatx4;
typedef __attribute__((ext_vector_type(4))) _Float16 half4;

static __device__ inline ushort bf16_rne(float x) {
  unsigned u = __float_as_uint(x);
  unsigned r = (u + 0x7fffu + ((u >> 16) & 1u)) >> 16;
  return (ushort)r;
}
static __device__ inline float bf16f(ushort h) { return __uint_as_float(((unsigned)h) << 16); }

static __device__ inline float ftanh(float x) {
  float e = __expf(2.0f * x);
  return 1.0f - 2.0f * __builtin_amdgcn_rcpf(e + 1.0f);
}

static __device__ inline void gl16(const void* g, void* l) {
  __builtin_amdgcn_global_load_lds(
      (const __attribute__((address_space(1))) unsigned int*)g,
      (__attribute__((address_space(3))) unsigned int*)l, 16, 0, 0);
}

// ---------------------------------------------------------------------------
// kQprep: Q -> per-(b,32q-tile) 48KB blobs: [SQhi 16K | SQlo 16K | TQhi 16K].
//  SQ: row-major hi/lo, granule j of row r at slot j^(r&7).
//  TQ: transposed [d][32q] bf16-hi only, granule k at slot k^((d>>1)&3).
// ---------------------------------------------------------------------------
__global__ __launch_bounds__(256) void kQprep(
    const float* __restrict__ ques, ushort* __restrict__ qb)
{
  const int b = blockIdx.y, qt = blockIdx.x;
  __shared__ float tile[32][260];
  const int tid = threadIdx.x;
  const float* src = ques + ((size_t)b * QQ + qt * 32) * DD;
  for (int i = tid; i < 32 * 64; i += 256) {
    int r = i >> 6, c = (i & 63) << 2;
    *(float4*)&tile[r][c] = *(const float4*)(src + r * DD + c);
  }
  __syncthreads();
  ushort* blob = qb + (size_t)(b * 32 + qt) * 24576;
  {
    int r = tid >> 3;
    int j0 = (tid & 7) * 4;
#pragma unroll
    for (int jj = 0; jj < 4; ++jj) {
      int j = j0 + jj;
      ushort h8[8], l8[8];
#pragma unroll
      for (int e = 0; e < 8; ++e) {
        float x = tile[r][j * 8 + e];
        ushort h = bf16_rne(x);
        h8[e] = h; l8[e] = bf16_rne(x - bf16f(h));
      }
      int g = r * 32 + (j ^ (r & 7));
      *(uint4*)&blob[(size_t)g * 8] = *(uint4*)h8;
      *(uint4*)&blob[8192 + (size_t)g * 8] = *(uint4*)l8;
    }
  }
  {
    int d = tid;
    int s = (d >> 1) & 3;
    ushort h32[32];
#pragma unroll
    for (int r = 0; r < 32; ++r) h32[r] = bf16_rne(tile[r][d]);
#pragma unroll
    for (int k = 0; k < 4; ++k)
      *(uint4*)&blob[16384 + (size_t)d * 32 + (k ^ s) * 8] = *(uint4*)&h32[k * 8];
  }
}

// ---------------------------------------------------------------------------
// kA: flash attention, cross-iteration pipelined (round-0 structure).
// 512 thr = 8 waves x 16 p-rows; triple-buffered 48KB Q tiles (1 block/CU).
// iter t: DMA(t+1) | GEMM1(t) | GEMM2(t-1) (P in regs) | softmax(t) | Ptrans(t).
// Fixed-shift softmax (C=60), l/rowmax reductions deferred to the end.
// Epilogue FUSES kB2: per-block q2c partials (weight e^{rowmax-60}).
// ---------------------------------------------------------------------------
__global__ __launch_bounds__(512, 1) void kA(
    const float* __restrict__ pass, const ushort* __restrict__ qb,
    const float* __restrict__ w_attn,
    _Float16* __restrict__ first_h, _Float16* __restrict__ tp_h,
    float* __restrict__ logit1,
    float* __restrict__ numpart, float* __restrict__ denpart)
{
  __shared__ alignas(16) char sm[147456];  // 3 x 48KB buffers

  const int b    = blockIdx.y;
  const int p0   = blockIdx.x * 128;
  const int tid  = threadIdx.x;
  const int w    = tid >> 6;
  const int lane = tid & 63;
  const int l15  = lane & 15;
  const int quad = lane >> 4;
  const int swz  = l15 & 7;

  // passage B-fragments (hi/lo), once per block
  short8 bhi[8], blo[8];
  {
    const float* prow = pass + (((size_t)b * PP + p0 + w * 16 + l15) * DD);
#pragma unroll
    for (int c = 0; c < 8; ++c) {
      const float* p8 = prow + c * 32 + quad * 8;
      float4 x0 = *(const float4*)p8;
      float4 x1 = *(const float4*)(p8 + 4);
      float xs[8] = {x0.x, x0.y, x0.z, x0.w, x1.x, x1.y, x1.z, x1.w};
#pragma unroll
      for (int j = 0; j < 8; ++j) {
        ushort h = bf16_rne(xs[j]);
        ushort lo = bf16_rne(xs[j] - bf16f(h));
        bhi[c][j] = (short)h;
        blo[c][j] = (short)lo;
      }
    }
  }

  int goff[8];
#pragma unroll
  for (int c = 0; c < 8; ++c) goff[c] = (l15 * 32 + ((4 * c + quad) ^ swz)) * 8;
  const int vtoff = l15 * 32 + ((quad ^ ((l15 >> 1) & 3)) * 8);

  const ushort* tb = qb + (size_t)b * 32 * 24576;
  const int dma_l = w * 3072 + lane * 8;   // ushort offset in blob
  const int dma_s = w * 6144 + lane * 16;  // byte offset in LDS buffer

  floatx4 accO[16];
#pragma unroll
  for (int i = 0; i < 16; ++i) accO[i] = (floatx4){0.f, 0.f, 0.f, 0.f};
  float mx = -INFINITY, ps = 0.f;
  short8 phi = {0, 0, 0, 0, 0, 0, 0, 0}, plo = {0, 0, 0, 0, 0, 0, 0, 0};

  // DMA(0) -> buf0
  {
    const ushort* gs = tb + dma_l;
    char* ld = sm + dma_s;
#pragma unroll
    for (int i = 0; i < 6; ++i) gl16(gs + i * 512, ld + i * 1024);
  }
  __syncthreads();

  for (int t = 0; t < 32; ++t) {
    const int ic = t % 3, ip = (t + 2) % 3, inx = (t + 1) % 3;
    char* cur = sm + ic * 49152;
    char* prv = sm + ip * 49152;
    if (t < 31) {
      const ushort* gs = tb + (size_t)(t + 1) * 24576 + dma_l;
      char* ld = sm + inx * 49152 + dma_s;
#pragma unroll
      for (int i = 0; i < 6; ++i) gl16(gs + i * 512, ld + i * 1024);
    }

    // ---- GEMM1(t): S^T(32q x 16p), 3-term split ----
    const ushort* Qhi = (const ushort*)cur;
    const ushort* Qlo = (const ushort*)(cur + 16384);
    floatx4 s0 = (floatx4){0.f, 0.f, 0.f, 0.f};
    floatx4 s1 = (floatx4){0.f, 0.f, 0.f, 0.f};
#pragma unroll
    for (int c = 0; c < 8; ++c) {
      short8 a0h = *(const short8*)&Qhi[goff[c]];
      short8 a0l = *(const short8*)&Qlo[goff[c]];
      short8 a1h = *(const short8*)&Qhi[goff[c] + 4096];
      short8 a1l = *(const short8*)&Qlo[goff[c] + 4096];
      s0 = __builtin_amdgcn_mfma_f32_16x16x32_bf16(a0h, bhi[c], s0, 0, 0, 0);
      s0 = __builtin_amdgcn_mfma_f32_16x16x32_bf16(a0h, blo[c], s0, 0, 0, 0);
      s0 = __builtin_amdgcn_mfma_f32_16x16x32_bf16(a0l, bhi[c], s0, 0, 0, 0);
      s1 = __builtin_amdgcn_mfma_f32_16x16x32_bf16(a1h, bhi[c], s1, 0, 0, 0);
      s1 = __builtin_amdgcn_mfma_f32_16x16x32_bf16(a1h, blo[c], s1, 0, 0, 0);
      s1 = __builtin_amdgcn_mfma_f32_16x16x32_bf16(a1l, bhi[c], s1, 0, 0, 0);
    }

    // ---- GEMM2(t-1): O += P(t-1)*Vhi(t-1), 2-term (phi,plo in regs) ----
    if (t > 0) {
      const ushort* TQ = (const ushort*)(prv + 32768);
#pragma unroll
      for (int nt = 0; nt < 16; ++nt) {
        short8 vhi = *(const short8*)&TQ[nt * 512 + vtoff];
        accO[nt] = __builtin_amdgcn_mfma_f32_16x16x32_bf16(phi, vhi, accO[nt], 0, 0, 0);
        accO[nt] = __builtin_amdgcn_mfma_f32_16x16x32_bf16(plo, vhi, accO[nt], 0, 0, 0);
      }
    }

    // ---- softmax(t): fixed shift, deferred reductions ----
    float pv[8];
#pragma unroll
    for (int r = 0; r < 4; ++r) {
      float s = s0[r];
      mx = fmaxf(mx, s);
      pv[r] = __expf(s - 60.f);
      ps += pv[r];
    }
#pragma unroll
    for (int r = 0; r < 4; ++r) {
      float s = s1[r];
      mx = fmaxf(mx, s);
      pv[4 + r] = __expf(s - 60.f);
      ps += pv[4 + r];
    }

    // ---- Ptrans(t): via dead SQhi of prv (same-wave, private slice) ----
    unsigned* pwv = (unsigned*)prv + w * 512;
#pragma unroll
    for (int mt = 0; mt < 2; ++mt) {
      unsigned pk[4];
#pragma unroll
      for (int r = 0; r < 4; ++r) {
        float x = pv[mt * 4 + r];
        ushort h = bf16_rne(x);
        ushort lo = bf16_rne(x - bf16f(h));
        pk[r] = (unsigned)h | ((unsigned)lo << 16);
      }
      int g = l15 * 8 + ((mt * 4 + quad) ^ swz);
      *(uint4*)&pwv[g * 4] = *(uint4*)pk;
    }
    uint4 u0 = *(const uint4*)&pwv[(l15 * 8 + ((2 * quad) ^ swz)) * 4];
    uint4 u1 = *(const uint4*)&pwv[(l15 * 8 + ((2 * quad + 1) ^ swz)) * 4];
    unsigned ua[8] = {u0.x, u0.y, u0.z, u0.w, u1.x, u1.y, u1.z, u1.w};
#pragma unroll
    for (int j = 0; j < 8; ++j) {
      phi[j] = (short)(ua[j] & 0xffffu);
      plo[j] = (short)(ua[j] >> 16);
    }
    __syncthreads();  // drain own DMA(t+1); phase boundary
  }

  // ---- GEMM2(31): tile 31 lives in buf[31%3 = 1] ----
  {
    const ushort* TQ = (const ushort*)(sm + 49152 + 32768);
#pragma unroll
    for (int nt = 0; nt < 16; ++nt) {
      short8 vhi = *(const short8*)&TQ[nt * 512 + vtoff];
      accO[nt] = __builtin_amdgcn_mfma_f32_16x16x32_bf16(phi, vhi, accO[nt], 0, 0, 0);
      accO[nt] = __builtin_amdgcn_mfma_f32_16x16x32_bf16(plo, vhi, accO[nt], 0, 0, 0);
    }
  }

  // ---- final reductions (once) ----
  ps += __shfl_xor(ps, 16);
  ps += __shfl_xor(ps, 32);
  mx = fmaxf(mx, __shfl_xor(mx, 16));
  mx = fmaxf(mx, __shfl_xor(mx, 32));

  // ---- epilogue ----
  __syncthreads();  // all waves done with buffers before Of scratch reuse
  float* Of = (float*)(sm + w * 16640);  // 16 x 260 fp32 per wave
#pragma unroll
  for (int nt = 0; nt < 16; ++nt)
#pragma unroll
    for (int r = 0; r < 4; ++r)
      Of[(quad * 4 + r) * 260 + nt * 16 + l15] = accO[nt][r];
  const float4 w1 = *(const float4*)(w_attn + lane * 4);
  const size_t rowoff = (size_t)b * PP + p0 + w * 16;
  float4 qacc = make_float4(0.f, 0.f, 0.f, 0.f);
  float dacc = 0.f;
#pragma unroll
  for (int j = 0; j < 16; ++j) {
    float4 o = *(const float4*)&Of[j * 260 + lane * 4];
    float linv = 1.f / __shfl(ps, j);
    float4 pv4 = *(const float4*)(pass + (rowoff + j) * DD + lane * 4);
    // fused kB2: q2c partial with weight e^{rowmax-60}
    float wj = __expf(__shfl(mx, j) - 60.f);
    qacc.x += wj * pv4.x; qacc.y += wj * pv4.y;
    qacc.z += wj * pv4.z; qacc.w += wj * pv4.w;
    dacc += wj;
    float tpx = ftanh(pv4.x), tpy = ftanh(pv4.y), tpz = ftanh(pv4.z), tpw = ftanh(pv4.w);
    float4 f;
    f.x = tpx * ftanh(o.x * linv);
    f.y = tpy * ftanh(o.y * linv);
    f.z = tpz * ftanh(o.z * linv);
    f.w = tpw * ftanh(o.w * linv);
    half4 fh = {(_Float16)f.x, (_Float16)f.y, (_Float16)f.z, (_Float16)f.w};
    half4 th = {(_Float16)tpx, (_Float16)tpy, (_Float16)tpz, (_Float16)tpw};
    *(half4*)(first_h + (rowoff + j) * DD + lane * 4) = fh;
    *(half4*)(tp_h + (rowoff + j) * DD + lane * 4) = th;
    float part = f.x * w1.x + f.y * w1.y + f.z * w1.z + f.w * w1.w;
    part += __shfl_xor(part, 1);  part += __shfl_xor(part, 2);
    part += __shfl_xor(part, 4);  part += __shfl_xor(part, 8);
    part += __shfl_xor(part, 16); part += __shfl_xor(part, 32);
    if (lane == 0) logit1[rowoff + j] = part;
  }

  // ---- fused kB2 reduction: 8 per-wave partials -> numpart/denpart ----
  float* redw = (float*)(sm + w * 16640);  // own Of slice, reads all done
  *(float4*)&redw[lane * 4] = qacc;
  if (lane == 0) redw[256] = dacc;
  __syncthreads();
  if (w == 0) {
    float4 s = make_float4(0.f, 0.f, 0.f, 0.f);
    float dsum = 0.f;
#pragma unroll
    for (int wv = 0; wv < 8; ++wv) {
      const float* rp = (const float*)(sm + wv * 16640);
      float4 v = *(const float4*)&rp[lane * 4];
      s.x += v.x; s.y += v.y; s.z += v.z; s.w += v.w;
      dsum += rp[256];
    }
    *(float4*)(numpart + (size_t)(blockIdx.x * 16 + b) * DD + lane * 4) = s;
    if (lane == 0) denpart[blockIdx.x * 16 + b] = dsum;
  }
}

// ---------------------------------------------------------------------------
// kE: fused kB3 + kC + reducer partials.  64 chunks x 64 p (4 blocks/CU).
// Per block: recompute w2tq from numpart/denpart (kB3's op order), then per
// row p: logit-dot from tp_h (kC's op order), wgt = exp(logit1 + dot);
// accumulate weighted f/t partials.
// ---------------------------------------------------------------------------
__global__ __launch_bounds__(256) void kE(
    const _Float16* __restrict__ tp_h, const _Float16* __restrict__ first_h,
    const float* __restrict__ logit1,
    const float* __restrict__ numpart, const float* __restrict__ denpart,
    const float* __restrict__ w_attn,
    float* __restrict__ r1part, float* __restrict__ r2part, float* __restrict__ den2part)
{
  const int b = blockIdx.y, chunk = blockIdx.x;   // 64 chunks x 64 p
  const int tid = threadIdx.x, r = tid >> 6, ln = tid & 63;
  __shared__ float s1[4][64][4];
  __shared__ float s2[4][64][4];
  __shared__ float sd[4][64];
  __shared__ alignas(16) float w2s[256];
  // fused kB3: w2tq[d] = w_attn[D+d] * tanh(sum num / sum den)
  {
    float num = 0.f, den = 0.f;
#pragma unroll
    for (int c = 0; c < 32; ++c) {
      num += numpart[(size_t)(c * 16 + b) * DD + tid];
      den += denpart[c * 16 + b];
    }
    w2s[tid] = w_attn[DD + tid] * ftanh(num / den);
  }
  __syncthreads();
  const float4 wv = *(const float4*)&w2s[ln << 2];
  const float* lg = logit1 + (size_t)b * PP + chunk * 64;
  const size_t base = ((size_t)b * PP + chunk * 64) * DD;
  float a1[4] = {0.f, 0.f, 0.f, 0.f}, a2[4] = {0.f, 0.f, 0.f, 0.f};
  float den = 0.f;
  for (int p = r; p < 64; p += 4) {
    half4 f = *(const half4*)(first_h + base + (size_t)p * DD + ln * 4);
    half4 t = *(const half4*)(tp_h + base + (size_t)p * DD + ln * 4);
    float part = (float)t.x * wv.x + (float)t.y * wv.y +
                 (float)t.z * wv.z + (float)t.w * wv.w;
    part += __shfl_xor(part, 1);  part += __shfl_xor(part, 2);
    part += __shfl_xor(part, 4);  part += __shfl_xor(part, 8);
    part += __shfl_xor(part, 16); part += __shfl_xor(part, 32);
    float wgt = __expf(lg[p] + part);
    a1[0] += wgt * (float)f.x; a1[1] += wgt * (float)f.y;
    a1[2] += wgt * (float)f.z; a1[3] += wgt * (float)f.w;
    a2[0] += wgt * (float)t.x; a2[1] += wgt * (float)t.y;
    a2[2] += wgt * (float)t.z; a2[3] += wgt * (float)t.w;
    den += wgt;
  }
  *(float4*)&s1[r][ln][0] = *(float4*)a1;
  *(float4*)&s2[r][ln][0] = *(float4*)a2;
  sd[r][ln] = den;
  __syncthreads();
  if (r == 0) {
    float o1[4], o2[4];
#pragma unroll
    for (int i = 0; i < 4; ++i) {
      o1[i] = s1[0][ln][i] + s1[1][ln][i] + s1[2][ln][i] + s1[3][ln][i];
      o2[i] = s2[0][ln][i] + s2[1][ln][i] + s2[2][ln][i] + s2[3][ln][i];
    }
    *(float4*)(r1part + (size_t)(chunk * 16 + b) * DD + ln * 4) = *(float4*)o1;
    *(float4*)(r2part + (size_t)(chunk * 16 + b) * DD + ln * 4) = *(float4*)o2;
    if (ln == 0)
      den2part[chunk * 16 + b] = sd[0][0] + sd[1][0] + sd[2][0] + sd[3][0];
  }
}

// ---------------------------------------------------------------------------
// kF: 64 blocks = (16 b x 4 o-groups).  Phase A: build R1/R2 in LDS
// (64-chunk reduction + tq recompute).  Phase B: 4-way k-split dot + reduce.
// ---------------------------------------------------------------------------
__global__ __launch_bounds__(256) void kF(
    const float* __restrict__ r1part, const float* __restrict__ r2part,
    const float* __restrict__ den2part,
    const float* __restrict__ numpart, const float* __restrict__ denpart,
    const float* __restrict__ w_out, const float* __restrict__ b_out,
    float* __restrict__ out)
{
  const int b = blockIdx.x >> 2, og = blockIdx.x & 3;
  const int tid = threadIdx.x;
  __shared__ alignas(16) float R1[256], R2[256];
  __shared__ float sacc[4][64];
  {
    float red1 = 0.f, red2 = 0.f, den2 = 0.f;
#pragma unroll
    for (int c = 0; c < 64; ++c) {
      red1 += r1part[(size_t)(c * 16 + b) * DD + tid];
      red2 += r2part[(size_t)(c * 16 + b) * DD + tid];
      den2 += den2part[c * 16 + b];
    }
    float num = 0.f, den = 0.f;
#pragma unroll
    for (int c = 0; c < 32; ++c) {
      num += numpart[(size_t)(c * 16 + b) * DD + tid];
      den += denpart[c * 16 + b];
    }
    float t = ftanh(num / den);
    float inv = 1.f / den2;
    R1[tid] = red1 * inv;
    R2[tid] = red2 * inv * t;
  }
  __syncthreads();
  const int oi = tid & 63, ks = tid >> 6;
  const int o = og * 64 + oi;
  float acc = 0.f;
  for (int k = ks * 64; k < ks * 64 + 64; ++k) {
    acc += R1[k] * w_out[k * 256 + o];
    acc += R2[k] * w_out[(DD + k) * 256 + o];
  }
  sacc[ks][oi] = acc;
  __syncthreads();
  if (ks == 0) {
    float v = sacc[0][oi] + sacc[1][oi] + sacc[2][oi] + sacc[3][oi];
    out[b * 256 + o] = v + b_out[o];
  }
}

extern "C" void kernel_launch(void* const* d_in, const int* in_sizes, int n_in,
                              void* d_out, int out_size, void* d_ws, size_t ws_size,
                              hipStream_t stream) {
  const float* pass   = (const float*)d_in[0];
  const float* ques   = (const float*)d_in[1];
  const float* w_attn = (const float*)d_in[2];
  // d_in[3] = b_attn: uniform softmax shift, cancels in num/den -> dropped
  const float* w_out  = (const float*)d_in[4];
  const float* b_out  = (const float*)d_in[5];
  float* out = (float*)d_out;

  float* ws       = (float*)d_ws;
  float* logit1   = ws;                                   // BB*PP
  float* numpart  = logit1   + (size_t)BB * PP;           // 32*BB*DD
  float* denpart  = numpart  + (size_t)32 * BB * DD;      // 32*BB
  float* r1part   = denpart  + 32 * BB;                   // 64*BB*DD
  float* r2part   = r1part   + (size_t)64 * BB * DD;      // 64*BB*DD
  float* den2part = r2part   + (size_t)64 * BB * DD;      // 64*BB
  ushort* qbb     = (ushort*)(den2part + 64 * BB);        // BB*32*24576 ushorts
  _Float16* first_h = (_Float16*)(qbb + (size_t)BB * 32 * 24576);
  _Float16* tp_h    = first_h + (size_t)BB * PP * DD;

  kQprep<<<dim3(QQ / 32, BB), 256, 0, stream>>>(ques, qbb);
  kA    <<<dim3(PP / 128, BB), 512, 0, stream>>>(pass, qbb, w_attn,
                                                 first_h, tp_h, logit1,
                                                 numpart, denpart);
  kE    <<<dim3(64, BB), 256, 0, stream>>>(tp_h, first_h, logit1,
                                           numpart, denpart, w_attn,
                                           r1part, r2part, den2part);
  kF    <<<64, 256, 0, stream>>>(r1part, r2part, den2part,
                                 numpart, denpart, w_out, b_out, out);
}